// Round 17
// baseline (200.849 us; speedup 1.0000x reference)
//
#include <hip/hip_runtime.h>

#define BN_EPS 1e-3f

typedef __attribute__((ext_vector_type(8))) short bf16x8;
typedef __attribute__((ext_vector_type(4))) short s16x4;
typedef __attribute__((ext_vector_type(4))) float f32x4;
typedef __attribute__((ext_vector_type(4))) unsigned u32x4;

// ---------------- bf16 split helpers ----------------
__device__ __forceinline__ unsigned short f2bf_rne(float f) {
  unsigned u = __float_as_uint(f);
  unsigned r = u + 0x7fffu + ((u >> 16) & 1u);
  return (unsigned short)(r >> 16);
}
__device__ __forceinline__ float bf2f(unsigned short h) {
  return __uint_as_float(((unsigned)h) << 16);
}
__device__ __forceinline__ void split2(float v, unsigned short& h, unsigned short& l) {
  h = f2bf_rne(v);
  l = f2bf_rne(v - bf2f(h));
}
// cheaper exact split: hi = truncated bf16 (bit AND), lo = RNE(v - hi).
__device__ __forceinline__ void split2t(float v, unsigned short& h, unsigned short& l) {
  unsigned u = __float_as_uint(v);
  float hi = __uint_as_float(u & 0xFFFF0000u);
  h = (unsigned short)(u >> 16);
  l = f2bf_rne(v - hi);
}
// packed split: returns (hi_trunc) | (lo_rne << 16) in one u32.
__device__ __forceinline__ unsigned pack_bf2(float v) {
  unsigned u = __float_as_uint(v);
  float lof = v - __uint_as_float(u & 0xFFFF0000u);
  unsigned lb = __float_as_uint(lof);
  unsigned rr = lb + 0x7fffu + ((lb >> 16) & 1u);
  return (u >> 16) | (rr & 0xFFFF0000u);
}

// ---------------- threefry2x32 (JAX partitionable path, key=[0,42]) --------
__device__ __forceinline__ unsigned rotl32(unsigned v, int n) {
  return (v << n) | (v >> (32 - n));
}

__device__ __forceinline__ float tf42_uniform(unsigned i) {
  unsigned x0 = 0u, x1 = i;
  const unsigned k0 = 0u, k1 = 42u, k2 = 0u ^ 42u ^ 0x1BD11BDAu;
  x0 += k0; x1 += k1;
#define TFR(r) { x0 += x1; x1 = rotl32(x1, r); x1 ^= x0; }
  TFR(13) TFR(15) TFR(26) TFR(6)
  x0 += k1; x1 += k2 + 1u;
  TFR(17) TFR(29) TFR(16) TFR(24)
  x0 += k2; x1 += k0 + 2u;
  TFR(13) TFR(15) TFR(26) TFR(6)
  x0 += k0; x1 += k1 + 3u;
  TFR(17) TFR(29) TFR(16) TFR(24)
  x0 += k1; x1 += k2 + 4u;
  TFR(13) TFR(15) TFR(26) TFR(6)
  x0 += k2; x1 += k0 + 5u;
#undef TFR
  unsigned bits = x0 ^ x1;
  return __uint_as_float((bits >> 9) | 0x3F800000u) - 1.0f;
}

// ---------------- K_prep_w: all static weight frags in one launch ----------
// blk 0..11: conv1 (3,3,4,32) -> [ks 3][nt 2][lane 64][8], invalid K -> 0
// blk 12..47: conv2 (3,3,32,32) -> [tap 9][nt 2][lane 64][8]
// blk 48: W2 (128,16) -> [ks 4][lane 64][8]
__global__ __launch_bounds__(256) void k_prep_w(
    const float* __restrict__ w1, const float* __restrict__ w2,
    const float* __restrict__ W2d,
    unsigned short* __restrict__ W1h, unsigned short* __restrict__ W1l,
    unsigned short* __restrict__ W2h_, unsigned short* __restrict__ W2l_,
    unsigned short* __restrict__ WD2h, unsigned short* __restrict__ WD2l) {
  int blk = blockIdx.x, tid = threadIdx.x;
  if (blk < 12) {
    int t = blk * 256 + tid;
    int j = t & 7, l = (t >> 3) & 63, nt = (t >> 9) & 1, ks = t >> 10;
    int k = 32 * ks + ((l >> 4) << 3) + j;
    int tap = k >> 3, ci = k & 7;
    float v = (tap < 9 && ci < 4) ? w1[tap * 128 + ci * 32 + nt * 16 + (l & 15)] : 0.f;
    unsigned short hh, ll; split2(v, hh, ll);
    W1h[t] = hh; W1l[t] = ll;
  } else if (blk < 48) {
    int t = (blk - 12) * 256 + tid;
    int j = t & 7, l = (t >> 3) & 63, nt = (t >> 9) & 1, tap = t >> 10;
    int ci = ((l >> 4) << 3) + j, co = nt * 16 + (l & 15);
    float v = w2[tap * 1024 + ci * 32 + co];
    unsigned short hh, ll; split2(v, hh, ll);
    W2h_[t] = hh; W2l_[t] = ll;
  } else {
    for (int t = tid; t < 2048; t += 256) {
      int j = t & 7, l = (t >> 3) & 63, ks = t >> 9;
      int k = 32 * ks + ((l >> 4) << 3) + j;
      int col = l & 15;
      float v = W2d[k * 16 + col];
      unsigned short hh, ll; split2(v, hh, ll);
      WD2h[t] = hh; WD2l[t] = ll;
    }
  }
}

// ---------------- K1: bn1 + conv1(4->32) + relu + maxpool2 + bn2 (MFMA) ----
__global__ __launch_bounds__(256) void k_conv1(
    const float* __restrict__ img,
    const float* __restrict__ g1, const float* __restrict__ be1,
    const float* __restrict__ m1, const float* __restrict__ v1,
    const unsigned short* __restrict__ Wc1h, const unsigned short* __restrict__ Wc1l,
    const float* __restrict__ bias,
    const float* __restrict__ g2, const float* __restrict__ be2,
    const float* __restrict__ m2, const float* __restrict__ v2,
    float* __restrict__ h1) {
  __shared__ __align__(16) unsigned short Lh[2592];  // 324 px * 8
  __shared__ __align__(16) unsigned short Ll[2592];
  int tid = threadIdx.x;
  int b = blockIdx.y;
  int tY = (blockIdx.x / 5) * 16, tX = (blockIdx.x % 5) * 16;
  float s1[4], t1[4];
#pragma unroll
  for (int ci = 0; ci < 4; ++ci) {
    float s = g1[ci] / sqrtf(v1[ci] + BN_EPS);
    s1[ci] = s; t1[ci] = be1[ci] - m1[ci] * s;
  }
  const s16x4 z4 = {0, 0, 0, 0};
  for (int idx = tid; idx < 324; idx += 256) {
    int ly = idx / 18, lx = idx - ly * 18;
    int gy = tY - 1 + ly, gx = tX - 1 + lx;
    float4 v = {0.f, 0.f, 0.f, 0.f};
    if (gy >= 0 && gy < 72 && gx >= 0 && gx < 72) {
      v = *(const float4*)(img + (((size_t)b * 72 + gy) * 72 + gx) * 4);
      v.x = v.x * s1[0] + t1[0];
      v.y = v.y * s1[1] + t1[1];
      v.z = v.z * s1[2] + t1[2];
      v.w = v.w * s1[3] + t1[3];
    }
    unsigned short ha, la, hb, lb, hc, lc, hd, ld;
    split2t(v.x, ha, la); split2t(v.y, hb, lb);
    split2t(v.z, hc, lc); split2t(v.w, hd, ld);
    s16x4 vh = {(short)ha, (short)hb, (short)hc, (short)hd};
    s16x4 vl = {(short)la, (short)lb, (short)lc, (short)ld};
    *(s16x4*)(Lh + idx * 8) = vh;
    *(s16x4*)(Lh + idx * 8 + 4) = z4;
    *(s16x4*)(Ll + idx * 8) = vl;
    *(s16x4*)(Ll + idx * 8 + 4) = z4;
  }
  __syncthreads();
  int wv = tid >> 6, lane = tid & 63;
  int lr = lane & 15, lhi = lane >> 4;
  int nt = wv & 1, mrow0 = (wv >> 1) * 8;
  bf16x8 wh[3], wl[3];
#pragma unroll
  for (int ks = 0; ks < 3; ++ks) {
    int base = ((ks * 2 + nt) * 64 + lane) * 8;
    wh[ks] = *(const bf16x8*)(Wc1h + base);
    wl[ks] = *(const bf16x8*)(Wc1l + base);
  }
  f32x4 acc[8];
#pragma unroll
  for (int mt = 0; mt < 8; ++mt) acc[mt] = (f32x4){0.f, 0.f, 0.f, 0.f};
#pragma unroll
  for (int ks = 0; ks < 3; ++ks) {
    int tap = 4 * ks + lhi;
    int tc = tap > 8 ? 8 : tap;  // invalid taps have B == 0
    int dy = tc / 3, dx = tc - 3 * dy;
#pragma unroll
    for (int mt = 0; mt < 8; ++mt) {
      int row = mrow0 + mt;
      int px = (row + dy) * 18 + lr + dx;
      bf16x8 ah = *(const bf16x8*)(Lh + px * 8);
      bf16x8 al = *(const bf16x8*)(Ll + px * 8);
      acc[mt] = __builtin_amdgcn_mfma_f32_16x16x32_bf16(ah, wh[ks], acc[mt], 0, 0, 0);
      acc[mt] = __builtin_amdgcn_mfma_f32_16x16x32_bf16(ah, wl[ks], acc[mt], 0, 0, 0);
      acc[mt] = __builtin_amdgcn_mfma_f32_16x16x32_bf16(al, wh[ks], acc[mt], 0, 0, 0);
    }
  }
  int co = nt * 16 + lr;
  float bv = bias[co];
  float s2 = g2[co] / sqrtf(v2[co] + BN_EPS);
  float t2 = be2[co] - m2[co] * s2;
#pragma unroll
  for (int a = 0; a < 4; ++a) {
#pragma unroll
    for (int bb = 0; bb < 2; ++bb) {
      float v00 = fmaxf(acc[2 * a][2 * bb] + bv, 0.f);
      float v01 = fmaxf(acc[2 * a][2 * bb + 1] + bv, 0.f);
      float v10 = fmaxf(acc[2 * a + 1][2 * bb] + bv, 0.f);
      float v11 = fmaxf(acc[2 * a + 1][2 * bb + 1] + bv, 0.f);
      float p = fmaxf(fmaxf(v00, v01), fmaxf(v10, v11));
      int gy = (tY >> 1) + (mrow0 >> 1) + a;
      int gx = (tX >> 1) + lhi * 2 + bb;
      if (gy < 36 && gx < 36)
        h1[(((size_t)b * 36 + gy) * 36 + gx) * 32 + co] = p * s2 + t2;
    }
  }
}

// ---------------- K2: conv2(32->32) + relu + maxpool2 (MFMA) ---------------
__global__ __launch_bounds__(256, 3) void k_conv2(
    const float* __restrict__ hin,
    const unsigned short* __restrict__ Wch, const unsigned short* __restrict__ Wcl,
    const float* __restrict__ bias, float* __restrict__ h2) {
  __shared__ __align__(16) unsigned short Lh[12960];  // 324 px * 40
  __shared__ __align__(16) unsigned short Ll[12960];
  int tid = threadIdx.x;
  int b = blockIdx.y;
  int tY = (blockIdx.x / 3) * 16, tX = (blockIdx.x % 3) * 16;
  for (int idx = tid; idx < 2592; idx += 256) {
    int pix = idx >> 3, c4 = idx & 7;
    int ly = pix / 18, lx = pix - ly * 18;
    int gy = tY - 1 + ly, gx = tX - 1 + lx;
    float4 v = {0.f, 0.f, 0.f, 0.f};
    if (gy >= 0 && gy < 36 && gx >= 0 && gx < 36)
      v = *(const float4*)(hin + (((size_t)b * 36 + gy) * 36 + gx) * 32 + c4 * 4);
    unsigned short ha, la, hb, lb, hc, lc, hd, ld;
    split2t(v.x, ha, la); split2t(v.y, hb, lb);
    split2t(v.z, hc, lc); split2t(v.w, hd, ld);
    s16x4 vh = {(short)ha, (short)hb, (short)hc, (short)hd};
    s16x4 vl = {(short)la, (short)lb, (short)lc, (short)ld};
    *(s16x4*)(Lh + pix * 40 + c4 * 4) = vh;
    *(s16x4*)(Ll + pix * 40 + c4 * 4) = vl;
  }
  __syncthreads();
  int wv = tid >> 6, lane = tid & 63;
  int lr = lane & 15, lhi = lane >> 4;
  int nt = wv & 1, mrow0 = (wv >> 1) * 8;
  bf16x8 wh[9], wl[9];
#pragma unroll
  for (int tap = 0; tap < 9; ++tap) {
    int base = ((tap * 2 + nt) * 64 + lane) * 8;
    wh[tap] = *(const bf16x8*)(Wch + base);
    wl[tap] = *(const bf16x8*)(Wcl + base);
  }
  f32x4 acc[8];
#pragma unroll
  for (int mt = 0; mt < 8; ++mt) acc[mt] = (f32x4){0.f, 0.f, 0.f, 0.f};
#pragma unroll
  for (int mt = 0; mt < 8; ++mt) {
    int row = mrow0 + mt;
#pragma unroll
    for (int tap = 0; tap < 9; ++tap) {
      int dy = tap / 3, dx = tap - dy * 3;
      int pixel = (row + dy) * 18 + (lr + dx);
      bf16x8 ah = *(const bf16x8*)(Lh + pixel * 40 + lhi * 8);
      bf16x8 al = *(const bf16x8*)(Ll + pixel * 40 + lhi * 8);
      acc[mt] = __builtin_amdgcn_mfma_f32_16x16x32_bf16(ah, wh[tap], acc[mt], 0, 0, 0);
      acc[mt] = __builtin_amdgcn_mfma_f32_16x16x32_bf16(ah, wl[tap], acc[mt], 0, 0, 0);
      acc[mt] = __builtin_amdgcn_mfma_f32_16x16x32_bf16(al, wh[tap], acc[mt], 0, 0, 0);
    }
  }
  int co = nt * 16 + lr;
  float bv = bias[co];
#pragma unroll
  for (int a = 0; a < 4; ++a) {
#pragma unroll
    for (int bb = 0; bb < 2; ++bb) {
      float v00 = fmaxf(acc[2 * a][2 * bb] + bv, 0.f);
      float v01 = fmaxf(acc[2 * a][2 * bb + 1] + bv, 0.f);
      float v10 = fmaxf(acc[2 * a + 1][2 * bb] + bv, 0.f);
      float v11 = fmaxf(acc[2 * a + 1][2 * bb + 1] + bv, 0.f);
      float p = fmaxf(fmaxf(v00, v01), fmaxf(v10, v11));
      int gy = (tY >> 1) + (mrow0 >> 1) + a;
      int gx = (tX >> 1) + lhi * 2 + bb;
      if (gy < 18 && gx < 18)
        h2[(((size_t)b * 18 + gy) * 18 + gx) * 32 + co] = p;
    }
  }
}

// ---------------- K3a: dense partial GEMM (K-split, MFMA split-bf16) -------
__global__ __launch_bounds__(256) void k_dense_part(
    const float* __restrict__ h2, const float* __restrict__ w,
    float* __restrict__ part) {
  __shared__ __align__(16) unsigned short Ah[128 * 40];
  __shared__ __align__(16) unsigned short Al[128 * 40];
  __shared__ __align__(16) unsigned short Bh[64 * 40];
  __shared__ __align__(16) unsigned short Bl[64 * 40];
  int tid = threadIdx.x;
  int n0 = blockIdx.x * 64;   // 14 blocks (last ragged)
  int kc = blockIdx.y;        // 18 K-chunks of 576
  int wv = tid >> 6, lane = tid & 63;
  int lr = lane & 15, lhi = lane >> 4;
  f32x4 acc[8];
#pragma unroll
  for (int m = 0; m < 8; ++m) acc[m] = (f32x4){0.f, 0.f, 0.f, 0.f};
  for (int kt = 0; kt < 18; ++kt) {
    int kb = kc * 576 + kt * 32;
    if (kt) __syncthreads();
#pragma unroll
    for (int it = 0; it < 4; ++it) {
      int f = tid + it * 256;  // 0..1023 : 128 m rows x 8 float4
      int ml = f >> 3, kq = f & 7;
      float4 p = *(const float4*)(h2 + (size_t)ml * 10368 + kb + kq * 4);
      unsigned short h0, l0, h1, l1, h2_, l2_, h3, l3;
      split2t(p.x, h0, l0); split2t(p.y, h1, l1);
      split2t(p.z, h2_, l2_); split2t(p.w, h3, l3);
      s16x4 vh = {(short)h0, (short)h1, (short)h2_, (short)h3};
      s16x4 vl = {(short)l0, (short)l1, (short)l2_, (short)l3};
      *(s16x4*)(Ah + ml * 40 + kq * 4) = vh;
      *(s16x4*)(Al + ml * 40 + kq * 4) = vl;
    }
#pragma unroll
    for (int it = 0; it < 2; ++it) {
      int f = tid + it * 256;  // 0..511 : 32 k rows x 16 float4
      int kr = f >> 4, n4 = (f & 15) * 4;
      float4 p = {0.f, 0.f, 0.f, 0.f};
      if (n0 + n4 < 864)
        p = *(const float4*)(w + (size_t)(kb + kr) * 864 + n0 + n4);
      unsigned short hh, ll;
      split2t(p.x, hh, ll); Bh[(n4 + 0) * 40 + kr] = hh; Bl[(n4 + 0) * 40 + kr] = ll;
      split2t(p.y, hh, ll); Bh[(n4 + 1) * 40 + kr] = hh; Bl[(n4 + 1) * 40 + kr] = ll;
      split2t(p.z, hh, ll); Bh[(n4 + 2) * 40 + kr] = hh; Bl[(n4 + 2) * 40 + kr] = ll;
      split2t(p.w, hh, ll); Bh[(n4 + 3) * 40 + kr] = hh; Bl[(n4 + 3) * 40 + kr] = ll;
    }
    __syncthreads();
    bf16x8 bh_ = *(const bf16x8*)(Bh + (wv * 16 + lr) * 40 + lhi * 8);
    bf16x8 bl_ = *(const bf16x8*)(Bl + (wv * 16 + lr) * 40 + lhi * 8);
#pragma unroll
    for (int m = 0; m < 8; ++m) {
      bf16x8 ah = *(const bf16x8*)(Ah + (m * 16 + lr) * 40 + lhi * 8);
      bf16x8 al = *(const bf16x8*)(Al + (m * 16 + lr) * 40 + lhi * 8);
      acc[m] = __builtin_amdgcn_mfma_f32_16x16x32_bf16(ah, bh_, acc[m], 0, 0, 0);
      acc[m] = __builtin_amdgcn_mfma_f32_16x16x32_bf16(ah, bl_, acc[m], 0, 0, 0);
      acc[m] = __builtin_amdgcn_mfma_f32_16x16x32_bf16(al, bh_, acc[m], 0, 0, 0);
    }
  }
  int n = n0 + wv * 16 + lr;
  if (n < 864) {
#pragma unroll
    for (int m = 0; m < 8; ++m) {
#pragma unroll
      for (int r = 0; r < 4; ++r) {
        int mm = m * 16 + lhi * 4 + r;
        part[((size_t)kc * 128 + mm) * 864 + n] = acc[m][r];
      }
    }
  }
}

// ---------------- K_finprep: reduce partials -> filt (LDS) -> W1eff frags --
__global__ __launch_bounds__(256) void k_finprep(
    const float* __restrict__ part, const float* __restrict__ bias,
    const float* __restrict__ W1,
    unsigned short* __restrict__ Eh, unsigned short* __restrict__ El) {
  __shared__ float fl[864];
  int b = blockIdx.x;
  int tid = threadIdx.x;
  for (int e = tid; e < 864; e += 256) {
    float s = bias[e];
#pragma unroll
    for (int kc = 0; kc < 18; ++kc) s += part[(size_t)kc * 110592 + b * 864 + e];
    fl[e] = fmaxf(s, 0.f);
  }
  __syncthreads();
  int col = tid & 127;
  int k0 = tid >> 7;
  for (int k = k0; k < 64; k += 2) {
    float v;
    if (k < 12) {
      v = W1[k * 128 + col];
    } else if (k < 48) {
      int h = (k - 12) / 3, t = (k - 12) % 3;
      const float* wp = W1 + (12 + t) * 128 + col;  // + c*384 walks rows 12+3c+t
      const float* fp = fl + h * 72;
      float a0 = 0.f, a1 = 0.f, a2 = 0.f, a3 = 0.f;
      for (int c = 0; c < 72; c += 4) {
        a0 = fmaf(fp[c], wp[(size_t)c * 384], a0);
        a1 = fmaf(fp[c + 1], wp[(size_t)(c + 1) * 384], a1);
        a2 = fmaf(fp[c + 2], wp[(size_t)(c + 2) * 384], a2);
        a3 = fmaf(fp[c + 3], wp[(size_t)(c + 3) * 384], a3);
      }
      v = (a0 + a1) + (a2 + a3);
    } else {
      v = 0.f;
    }
    unsigned short hh, ll;
    split2(v, hh, ll);
    int ks = k >> 5, j = k & 7, a4 = (k >> 3) & 3;
    int l = a4 * 16 + (col & 15), nt = col >> 4;
    size_t o = (((size_t)b * 8 + nt) * 2 + ks) * 512 + l * 8 + j;
    Eh[o] = hh;
    El[o] = ll;
  }
}

// ---------------- K4: fused CA update (halved u-exchange, 6 blocks/CU) -----
__global__ __launch_bounds__(256, 6) void k_ca(
    const float* __restrict__ x,
    const unsigned short* __restrict__ Eh, const unsigned short* __restrict__ El,
    const float* __restrict__ B1,
    const unsigned short* __restrict__ W2h, const unsigned short* __restrict__ W2l,
    const float* __restrict__ B2,
    float* __restrict__ xnew, float* __restrict__ aold,
    float* __restrict__ anew) {
  // staging: ia [16][120] f32 @0 (7680) | PAh @7680 (9216) | PAl @16896 (9216)
  // -> 26112. Union after main GEMM: U32 @0 [64 px][68] u32 (17408) holds ONE
  // 64-hid half of u at a time. mskL @26112 (256). Total 26368 -> 6 blk/CU.
  __shared__ __align__(16) unsigned char S[26368];
  float* ia = (float*)S;
  unsigned short* PAh = (unsigned short*)(S + 7680);
  unsigned short* PAl = (unsigned short*)(S + 16896);
  unsigned* U32 = (unsigned*)S;
  float* mskL = (float*)(S + 26112);

  int tid = threadIdx.x;
  int b = blockIdx.y;
  int tx = (blockIdx.x & 7) * 8, ty = (blockIdx.x >> 3) * 8;
  int wv = tid >> 6, lane = tid & 63;
  int lr = lane & 15, lhi = lane >> 4;

  // prefetch W1eff B-frags (global, hides under phase A)
  bf16x8 bh[2][2], bl[2][2];
#pragma unroll
  for (int nt = 0; nt < 2; ++nt)
#pragma unroll
    for (int ks = 0; ks < 2; ++ks) {
      size_t base = (((size_t)b * 8 + (wv * 2 + nt)) * 2 + ks) * 512 + lane * 8;
      bh[nt][ks] = *(const bf16x8*)(Eh + base);
      bl[nt][ks] = *(const bf16x8*)(El + base);
    }
  // prefetch xo for phase D: px = wv*16 + lhi*4 + r, channel lr
  float xo[4];
#pragma unroll
  for (int r = 0; r < 4; ++r) {
    int px = wv * 16 + lhi * 4 + r;
    int gy = ty + (px >> 3), gx = tx + (px & 7);
    xo[r] = x[(((size_t)b * 64 + gy) * 64 + gx) * 16 + lr];
  }

  // ---- phase A: x halo -> ia; threefry -> mskL; zero PA k-pad 48..63
  if (tid < 200) {
    int px_ = tid >> 1, half = tid & 1;
    int hy = px_ / 10, hx = px_ - hy * 10;
    int pp = hy * 12 + hx;
    int gy = ty + hy - 1, gx = tx + hx - 1;
    float4 v0 = {0.f, 0.f, 0.f, 0.f}, v1 = {0.f, 0.f, 0.f, 0.f};
    if (gy >= 0 && gy < 64 && gx >= 0 && gx < 64) {
      const float* xp = x + (((size_t)b * 64 + gy) * 64 + gx) * 16 + half * 8;
      v0 = *(const float4*)xp;
      v1 = *(const float4*)(xp + 4);
    }
    int c0 = half * 8;
    ia[(c0 + 0) * 120 + pp] = v0.x; ia[(c0 + 1) * 120 + pp] = v0.y;
    ia[(c0 + 2) * 120 + pp] = v0.z; ia[(c0 + 3) * 120 + pp] = v0.w;
    ia[(c0 + 4) * 120 + pp] = v1.x; ia[(c0 + 5) * 120 + pp] = v1.y;
    ia[(c0 + 6) * 120 + pp] = v1.z; ia[(c0 + 7) * 120 + pp] = v1.w;
  }
  {
    if (tid >= 192) {
      int p = tid - 192;
      int gy = ty + (p >> 3), gx = tx + (p & 7);
      unsigned pix = (unsigned)(b * 4096 + gy * 64 + gx);
      mskL[p] = (tf42_uniform(pix) <= 0.5f) ? 1.f : 0.f;
    }
    const s16x4 z4 = {0, 0, 0, 0};
    if (wv == 2) {
#pragma unroll
      for (int g = 0; g < 4; ++g) *(s16x4*)(PAh + lane * 72 + 48 + 4 * g) = z4;
    }
    if (wv == 3) {
#pragma unroll
      for (int g = 0; g < 4; ++g) *(s16x4*)(PAl + lane * 72 + 48 + 4 * g) = z4;
    }
  }
  __syncthreads();

  // ---- phase P: perception of ch 4wv..4wv+3 -> PA cols 12wv..12wv+11
  {
    int py = lane >> 3, pxx = lane & 7;
    const float* pc0 = ia + (py + 1) * 12 + (pxx + 1);
    unsigned short oh[12], ol[12];
#pragma unroll
    for (int i = 0; i < 4; ++i) {
      const float* pc = pc0 + (wv * 4 + i) * 120;
      float n00 = pc[-13], n01 = pc[-12], n02 = pc[-11];
      float n10 = pc[-1],  n11 = pc[0],   n12 = pc[1];
      float n20 = pc[11],  n21 = pc[12],  n22 = pc[13];
      float pid = n11;
      float psx = ((n02 - n00) + 2.f * (n12 - n10) + (n22 - n20)) * 0.125f;
      float psy = ((n20 - n00) + 2.f * (n21 - n01) + (n22 - n02)) * 0.125f;
      split2t(pid, oh[3 * i + 0], ol[3 * i + 0]);
      split2t(psx, oh[3 * i + 1], ol[3 * i + 1]);
      split2t(psy, oh[3 * i + 2], ol[3 * i + 2]);
    }
    int off = lane * 72 + wv * 12;
#pragma unroll
    for (int g = 0; g < 3; ++g) {
      s16x4 vh = {(short)oh[4 * g], (short)oh[4 * g + 1],
                  (short)oh[4 * g + 2], (short)oh[4 * g + 3]};
      s16x4 vl = {(short)ol[4 * g], (short)ol[4 * g + 1],
                  (short)ol[4 * g + 2], (short)ol[4 * g + 3]};
      *(s16x4*)(PAh + off + 4 * g) = vh;
      *(s16x4*)(PAl + off + 4 * g) = vl;
    }
  }
  __syncthreads();

  // ---- phase M: main GEMM, 2 ks x 4 m x 2 nt x 3 passes
  f32x4 acc[4][2];
#pragma unroll
  for (int m = 0; m < 4; ++m)
#pragma unroll
    for (int nt = 0; nt < 2; ++nt)
      acc[m][nt] = (f32x4){0.f, 0.f, 0.f, 0.f};
#pragma unroll
  for (int ks = 0; ks < 2; ++ks) {
#pragma unroll
    for (int m = 0; m < 4; ++m) {
      int arow = m * 16 + lr;
      bf16x8 pah = *(const bf16x8*)(PAh + arow * 72 + ks * 32 + lhi * 8);
      bf16x8 pal = *(const bf16x8*)(PAl + arow * 72 + ks * 32 + lhi * 8);
#pragma unroll
      for (int nt = 0; nt < 2; ++nt) {
        acc[m][nt] = __builtin_amdgcn_mfma_f32_16x16x32_bf16(
            pah, bh[nt][ks], acc[m][nt], 0, 0, 0);
        acc[m][nt] = __builtin_amdgcn_mfma_f32_16x16x32_bf16(
            pah, bl[nt][ks], acc[m][nt], 0, 0, 0);
        acc[m][nt] = __builtin_amdgcn_mfma_f32_16x16x32_bf16(
            pal, bh[nt][ks], acc[m][nt], 0, 0, 0);
      }
    }
  }
  // prefetch W2 frags (consumed after next barrier)
  bf16x8 ch_[4], cl_[4];
#pragma unroll
  for (int ks = 0; ks < 4; ++ks) {
    ch_[ks] = *(const bf16x8*)(W2h + ks * 512 + lane * 8);
    cl_[ks] = *(const bf16x8*)(W2l + ks * 512 + lane * 8);
  }

  // ---- halved u-exchange + dx MFMA: two 64-hid halves through U32[64][68]
  // wave wv owns hid d0 = wv*32 (half h = wv>>1, local base = (wv&1)*32).
  int d0 = wv * 32;
  float b1v0 = B1[d0 + lr], b1v1 = B1[d0 + 16 + lr];
  union Cvt { unsigned d[4]; bf16x8 v8; };
  f32x4 acc2 = {0.f, 0.f, 0.f, 0.f};
  const unsigned* urow = U32 + (wv * 16 + lr) * 68;
#pragma unroll
  for (int h = 0; h < 2; ++h) {
    __syncthreads();  // h=0: PA dead; h=1: half-0 reads done
    if ((wv >> 1) == h) {
      int hidloc = (wv & 1) * 32 + lr;
#pragma unroll
      for (int m = 0; m < 4; ++m)
#pragma unroll
        for (int nt = 0; nt < 2; ++nt) {
          float bv = nt ? b1v1 : b1v0;
#pragma unroll
          for (int r = 0; r < 4; ++r) {
            int px = m * 16 + lhi * 4 + r;
            U32[px * 68 + hidloc + nt * 16] =
                pack_bf2(fmaxf(acc[m][nt][r] + bv, 0.f));
          }
        }
    }
    __syncthreads();
#pragma unroll
    for (int ksl = 0; ksl < 2; ++ksl) {
      int ks = h * 2 + ksl;
      u32x4 q0 = *(const u32x4*)(urow + ksl * 32 + lhi * 8);
      u32x4 q1 = *(const u32x4*)(urow + ksl * 32 + lhi * 8 + 4);
      Cvt ah, al;
#pragma unroll
      for (int i = 0; i < 2; ++i) {
        unsigned p0 = q0[2 * i], p1 = q0[2 * i + 1];
        ah.d[i] = (p0 & 0xffffu) | (p1 << 16);
        al.d[i] = (p0 >> 16) | (p1 & 0xffff0000u);
      }
#pragma unroll
      for (int i = 0; i < 2; ++i) {
        unsigned p0 = q1[2 * i], p1 = q1[2 * i + 1];
        ah.d[2 + i] = (p0 & 0xffffu) | (p1 << 16);
        al.d[2 + i] = (p0 >> 16) | (p1 & 0xffff0000u);
      }
      acc2 = __builtin_amdgcn_mfma_f32_16x16x32_bf16(ah.v8, ch_[ks], acc2, 0, 0, 0);
      acc2 = __builtin_amdgcn_mfma_f32_16x16x32_bf16(ah.v8, cl_[ks], acc2, 0, 0, 0);
      acc2 = __builtin_amdgcn_mfma_f32_16x16x32_bf16(al.v8, ch_[ks], acc2, 0, 0, 0);
    }
  }

  // ---- phase D: dx + fire mask + write x_new + alphas (lane holds e=lr)
  float b2v = B2[lr];
#pragma unroll
  for (int r = 0; r < 4; ++r) {
    int px = wv * 16 + lhi * 4 + r;
    int gy = ty + (px >> 3), gx = tx + (px & 7);
    float m_ = mskL[px];
    float xn = xo[r] + (acc2[r] + b2v) * m_;
    size_t o = (((size_t)b * 64 + gy) * 64 + gx) * 16 + lr;
    xnew[o] = xn;
    if (lr == 3) {
      unsigned pix = (unsigned)(b * 4096 + gy * 64 + gx);
      aold[pix] = xo[r];
      anew[pix] = xn;
    }
  }
}

// ---------------- K5: living mask; ZERO only dead pixels (in place) --------
__global__ __launch_bounds__(256) void k_final(
    float* __restrict__ xnew, const float* __restrict__ aold,
    const float* __restrict__ anew) {
  int t = blockIdx.x * 256 + threadIdx.x;  // grid 2048*256 = 524288
  int gx = t & 63, gy = (t >> 6) & 63, b = t >> 12;
  float mo = -1e30f, mn = -1e30f;
  for (int dy = -1; dy <= 1; ++dy) {
    int yy = gy + dy; if (yy < 0 || yy >= 64) continue;
    for (int dx = -1; dx <= 1; ++dx) {
      int xx = gx + dx; if (xx < 0 || xx >= 64) continue;
      int p = b * 4096 + yy * 64 + xx;
      mo = fmaxf(mo, aold[p]);
      mn = fmaxf(mn, anew[p]);
    }
  }
  if (!(mo > 0.1f && mn > 0.1f)) {
    size_t base = (size_t)t * 16;
    const float4 z = {0.f, 0.f, 0.f, 0.f};
#pragma unroll
    for (int c4 = 0; c4 < 4; ++c4)
      *(float4*)(xnew + base + c4 * 4) = z;
  }
}

// ---------------- launch ----------------
extern "C" void kernel_launch(void* const* d_in, const int* in_sizes, int n_in,
                              void* d_out, int out_size, void* d_ws, size_t ws_size,
                              hipStream_t stream) {
  const float* x    = (const float*)d_in[0];
  const float* img  = (const float*)d_in[1];
  const float* g1   = (const float*)d_in[2];
  const float* be1  = (const float*)d_in[3];
  const float* m1   = (const float*)d_in[4];
  const float* v1   = (const float*)d_in[5];
  const float* w1c  = (const float*)d_in[6];
  const float* b1c  = (const float*)d_in[7];
  const float* g2   = (const float*)d_in[8];
  const float* be2  = (const float*)d_in[9];
  const float* m2   = (const float*)d_in[10];
  const float* v2   = (const float*)d_in[11];
  const float* w2c  = (const float*)d_in[12];
  const float* b2c  = (const float*)d_in[13];
  const float* dw   = (const float*)d_in[14];
  const float* db   = (const float*)d_in[15];
  const float* uw1  = (const float*)d_in[16];
  const float* ub1  = (const float*)d_in[17];
  const float* uw2  = (const float*)d_in[18];
  const float* ub2  = (const float*)d_in[19];

  char* ws = (char*)d_ws;
  float* h1   = (float*)(ws);                        // 21,233,664 B (dead after conv2)
  float* part = h1;                                  // aliased (written by dense)
  float* h2   = (float*)(ws + 21233664);             // 5,308,416 B
  float* aold = (float*)(ws + 26542080);             // 2,097,152 B
  float* anew = (float*)(ws + 28639232);             // 2,097,152 B
  unsigned short* W2Bh = (unsigned short*)(ws + 30736384);  // 4,096 B
  unsigned short* W2Bl = (unsigned short*)(ws + 30740480);  // 4,096 B
  unsigned short* Wc2h = (unsigned short*)(ws + 30744576);  // 18,432 B
  unsigned short* Wc2l = (unsigned short*)(ws + 30763008);  // 18,432 B
  unsigned short* Wc1h = (unsigned short*)(ws + 30781440);  // 6,144 B
  unsigned short* Wc1l = (unsigned short*)(ws + 30787584);  // 6,144 B
  unsigned short* W1Eh = (unsigned short*)(ws + 30793728);  // 2,097,152 B
  unsigned short* W1El = (unsigned short*)(ws + 32890880);  // 2,097,152 B
  // total 34,988,032 B
  float* xnew = (float*)d_out;                       // (128,64,64,16) f32

  k_prep_w<<<49, 256, 0, stream>>>(w1c, w2c, uw2, Wc1h, Wc1l, Wc2h, Wc2l,
                                   W2Bh, W2Bl);
  k_conv1<<<dim3(25, 128), 256, 0, stream>>>(img, g1, be1, m1, v1, Wc1h, Wc1l,
                                             b1c, g2, be2, m2, v2, h1);
  k_conv2<<<dim3(9, 128), 256, 0, stream>>>(h1, Wc2h, Wc2l, b2c, h2);
  k_dense_part<<<dim3(14, 18), 256, 0, stream>>>(h2, dw, part);
  k_finprep<<<128, 256, 0, stream>>>(part, db, uw1, W1Eh, W1El);
  k_ca<<<dim3(64, 128), 256, 0, stream>>>(x, W1Eh, W1El, ub1, W2Bh, W2Bl, ub2,
                                          xnew, aold, anew);
  k_final<<<2048, 256, 0, stream>>>(xnew, aold, anew);
}

// Round 18
// 174.275 us; speedup vs baseline: 1.1525x; 1.1525x over previous
//
#include <hip/hip_runtime.h>

#define BN_EPS 1e-3f

typedef __attribute__((ext_vector_type(8))) short bf16x8;
typedef __attribute__((ext_vector_type(4))) short s16x4;
typedef __attribute__((ext_vector_type(4))) float f32x4;
typedef __attribute__((ext_vector_type(4))) unsigned u32x4;

// ---------------- bf16 split helpers ----------------
__device__ __forceinline__ unsigned short f2bf_rne(float f) {
  unsigned u = __float_as_uint(f);
  unsigned r = u + 0x7fffu + ((u >> 16) & 1u);
  return (unsigned short)(r >> 16);
}
__device__ __forceinline__ float bf2f(unsigned short h) {
  return __uint_as_float(((unsigned)h) << 16);
}
__device__ __forceinline__ void split2(float v, unsigned short& h, unsigned short& l) {
  h = f2bf_rne(v);
  l = f2bf_rne(v - bf2f(h));
}
// cheaper exact split: hi = truncated bf16 (bit AND), lo = RNE(v - hi).
__device__ __forceinline__ void split2t(float v, unsigned short& h, unsigned short& l) {
  unsigned u = __float_as_uint(v);
  float hi = __uint_as_float(u & 0xFFFF0000u);
  h = (unsigned short)(u >> 16);
  l = f2bf_rne(v - hi);
}
// packed split: returns (hi_trunc) | (lo_rne << 16) in one u32.
__device__ __forceinline__ unsigned pack_bf2(float v) {
  unsigned u = __float_as_uint(v);
  float lof = v - __uint_as_float(u & 0xFFFF0000u);
  unsigned lb = __float_as_uint(lof);
  unsigned rr = lb + 0x7fffu + ((lb >> 16) & 1u);
  return (u >> 16) | (rr & 0xFFFF0000u);
}

// ---------------- threefry2x32 (JAX partitionable path, key=[0,42]) --------
__device__ __forceinline__ unsigned rotl32(unsigned v, int n) {
  return (v << n) | (v >> (32 - n));
}

__device__ __forceinline__ float tf42_uniform(unsigned i) {
  unsigned x0 = 0u, x1 = i;
  const unsigned k0 = 0u, k1 = 42u, k2 = 0u ^ 42u ^ 0x1BD11BDAu;
  x0 += k0; x1 += k1;
#define TFR(r) { x0 += x1; x1 = rotl32(x1, r); x1 ^= x0; }
  TFR(13) TFR(15) TFR(26) TFR(6)
  x0 += k1; x1 += k2 + 1u;
  TFR(17) TFR(29) TFR(16) TFR(24)
  x0 += k2; x1 += k0 + 2u;
  TFR(13) TFR(15) TFR(26) TFR(6)
  x0 += k0; x1 += k1 + 3u;
  TFR(17) TFR(29) TFR(16) TFR(24)
  x0 += k1; x1 += k2 + 4u;
  TFR(13) TFR(15) TFR(26) TFR(6)
  x0 += k2; x1 += k0 + 5u;
#undef TFR
  unsigned bits = x0 ^ x1;
  return __uint_as_float((bits >> 9) | 0x3F800000u) - 1.0f;
}

// ---------------- K_prep_w: all static weight frags in one launch ----------
// blk 0..11: conv1 (3,3,4,32) -> [ks 3][nt 2][lane 64][8], invalid K -> 0
// blk 12..47: conv2 (3,3,32,32) -> [tap 9][nt 2][lane 64][8]
// blk 48: W2 (128,16) -> [ks 4][lane 64][8]
__global__ __launch_bounds__(256) void k_prep_w(
    const float* __restrict__ w1, const float* __restrict__ w2,
    const float* __restrict__ W2d,
    unsigned short* __restrict__ W1h, unsigned short* __restrict__ W1l,
    unsigned short* __restrict__ W2h_, unsigned short* __restrict__ W2l_,
    unsigned short* __restrict__ WD2h, unsigned short* __restrict__ WD2l) {
  int blk = blockIdx.x, tid = threadIdx.x;
  if (blk < 12) {
    int t = blk * 256 + tid;
    int j = t & 7, l = (t >> 3) & 63, nt = (t >> 9) & 1, ks = t >> 10;
    int k = 32 * ks + ((l >> 4) << 3) + j;
    int tap = k >> 3, ci = k & 7;
    float v = (tap < 9 && ci < 4) ? w1[tap * 128 + ci * 32 + nt * 16 + (l & 15)] : 0.f;
    unsigned short hh, ll; split2(v, hh, ll);
    W1h[t] = hh; W1l[t] = ll;
  } else if (blk < 48) {
    int t = (blk - 12) * 256 + tid;
    int j = t & 7, l = (t >> 3) & 63, nt = (t >> 9) & 1, tap = t >> 10;
    int ci = ((l >> 4) << 3) + j, co = nt * 16 + (l & 15);
    float v = w2[tap * 1024 + ci * 32 + co];
    unsigned short hh, ll; split2(v, hh, ll);
    W2h_[t] = hh; W2l_[t] = ll;
  } else {
    for (int t = tid; t < 2048; t += 256) {
      int j = t & 7, l = (t >> 3) & 63, ks = t >> 9;
      int k = 32 * ks + ((l >> 4) << 3) + j;
      int col = l & 15;
      float v = W2d[k * 16 + col];
      unsigned short hh, ll; split2(v, hh, ll);
      WD2h[t] = hh; WD2l[t] = ll;
    }
  }
}

// ---------------- K1: bn1 + conv1(4->32) + relu + maxpool2 + bn2 (MFMA) ----
__global__ __launch_bounds__(256) void k_conv1(
    const float* __restrict__ img,
    const float* __restrict__ g1, const float* __restrict__ be1,
    const float* __restrict__ m1, const float* __restrict__ v1,
    const unsigned short* __restrict__ Wc1h, const unsigned short* __restrict__ Wc1l,
    const float* __restrict__ bias,
    const float* __restrict__ g2, const float* __restrict__ be2,
    const float* __restrict__ m2, const float* __restrict__ v2,
    float* __restrict__ h1) {
  __shared__ __align__(16) unsigned short Lh[2592];  // 324 px * 8
  __shared__ __align__(16) unsigned short Ll[2592];
  int tid = threadIdx.x;
  int b = blockIdx.y;
  int tY = (blockIdx.x / 5) * 16, tX = (blockIdx.x % 5) * 16;
  float s1[4], t1[4];
#pragma unroll
  for (int ci = 0; ci < 4; ++ci) {
    float s = g1[ci] / sqrtf(v1[ci] + BN_EPS);
    s1[ci] = s; t1[ci] = be1[ci] - m1[ci] * s;
  }
  const s16x4 z4 = {0, 0, 0, 0};
  for (int idx = tid; idx < 324; idx += 256) {
    int ly = idx / 18, lx = idx - ly * 18;
    int gy = tY - 1 + ly, gx = tX - 1 + lx;
    float4 v = {0.f, 0.f, 0.f, 0.f};
    if (gy >= 0 && gy < 72 && gx >= 0 && gx < 72) {
      v = *(const float4*)(img + (((size_t)b * 72 + gy) * 72 + gx) * 4);
      v.x = v.x * s1[0] + t1[0];
      v.y = v.y * s1[1] + t1[1];
      v.z = v.z * s1[2] + t1[2];
      v.w = v.w * s1[3] + t1[3];
    }
    unsigned short ha, la, hb, lb, hc, lc, hd, ld;
    split2t(v.x, ha, la); split2t(v.y, hb, lb);
    split2t(v.z, hc, lc); split2t(v.w, hd, ld);
    s16x4 vh = {(short)ha, (short)hb, (short)hc, (short)hd};
    s16x4 vl = {(short)la, (short)lb, (short)lc, (short)ld};
    *(s16x4*)(Lh + idx * 8) = vh;
    *(s16x4*)(Lh + idx * 8 + 4) = z4;
    *(s16x4*)(Ll + idx * 8) = vl;
    *(s16x4*)(Ll + idx * 8 + 4) = z4;
  }
  __syncthreads();
  int wv = tid >> 6, lane = tid & 63;
  int lr = lane & 15, lhi = lane >> 4;
  int nt = wv & 1, mrow0 = (wv >> 1) * 8;
  bf16x8 wh[3], wl[3];
#pragma unroll
  for (int ks = 0; ks < 3; ++ks) {
    int base = ((ks * 2 + nt) * 64 + lane) * 8;
    wh[ks] = *(const bf16x8*)(Wc1h + base);
    wl[ks] = *(const bf16x8*)(Wc1l + base);
  }
  f32x4 acc[8];
#pragma unroll
  for (int mt = 0; mt < 8; ++mt) acc[mt] = (f32x4){0.f, 0.f, 0.f, 0.f};
#pragma unroll
  for (int ks = 0; ks < 3; ++ks) {
    int tap = 4 * ks + lhi;
    int tc = tap > 8 ? 8 : tap;  // invalid taps have B == 0
    int dy = tc / 3, dx = tc - 3 * dy;
#pragma unroll
    for (int mt = 0; mt < 8; ++mt) {
      int row = mrow0 + mt;
      int px = (row + dy) * 18 + lr + dx;
      bf16x8 ah = *(const bf16x8*)(Lh + px * 8);
      bf16x8 al = *(const bf16x8*)(Ll + px * 8);
      acc[mt] = __builtin_amdgcn_mfma_f32_16x16x32_bf16(ah, wh[ks], acc[mt], 0, 0, 0);
      acc[mt] = __builtin_amdgcn_mfma_f32_16x16x32_bf16(ah, wl[ks], acc[mt], 0, 0, 0);
      acc[mt] = __builtin_amdgcn_mfma_f32_16x16x32_bf16(al, wh[ks], acc[mt], 0, 0, 0);
    }
  }
  int co = nt * 16 + lr;
  float bv = bias[co];
  float s2 = g2[co] / sqrtf(v2[co] + BN_EPS);
  float t2 = be2[co] - m2[co] * s2;
#pragma unroll
  for (int a = 0; a < 4; ++a) {
#pragma unroll
    for (int bb = 0; bb < 2; ++bb) {
      float v00 = fmaxf(acc[2 * a][2 * bb] + bv, 0.f);
      float v01 = fmaxf(acc[2 * a][2 * bb + 1] + bv, 0.f);
      float v10 = fmaxf(acc[2 * a + 1][2 * bb] + bv, 0.f);
      float v11 = fmaxf(acc[2 * a + 1][2 * bb + 1] + bv, 0.f);
      float p = fmaxf(fmaxf(v00, v01), fmaxf(v10, v11));
      int gy = (tY >> 1) + (mrow0 >> 1) + a;
      int gx = (tX >> 1) + lhi * 2 + bb;
      if (gy < 36 && gx < 36)
        h1[(((size_t)b * 36 + gy) * 36 + gx) * 32 + co] = p * s2 + t2;
    }
  }
}

// ---------------- K2: conv2(32->32) + relu + maxpool2 (MFMA) ---------------
__global__ __launch_bounds__(256, 3) void k_conv2(
    const float* __restrict__ hin,
    const unsigned short* __restrict__ Wch, const unsigned short* __restrict__ Wcl,
    const float* __restrict__ bias, float* __restrict__ h2) {
  __shared__ __align__(16) unsigned short Lh[12960];  // 324 px * 40
  __shared__ __align__(16) unsigned short Ll[12960];
  int tid = threadIdx.x;
  int b = blockIdx.y;
  int tY = (blockIdx.x / 3) * 16, tX = (blockIdx.x % 3) * 16;
  for (int idx = tid; idx < 2592; idx += 256) {
    int pix = idx >> 3, c4 = idx & 7;
    int ly = pix / 18, lx = pix - ly * 18;
    int gy = tY - 1 + ly, gx = tX - 1 + lx;
    float4 v = {0.f, 0.f, 0.f, 0.f};
    if (gy >= 0 && gy < 36 && gx >= 0 && gx < 36)
      v = *(const float4*)(hin + (((size_t)b * 36 + gy) * 36 + gx) * 32 + c4 * 4);
    unsigned short ha, la, hb, lb, hc, lc, hd, ld;
    split2t(v.x, ha, la); split2t(v.y, hb, lb);
    split2t(v.z, hc, lc); split2t(v.w, hd, ld);
    s16x4 vh = {(short)ha, (short)hb, (short)hc, (short)hd};
    s16x4 vl = {(short)la, (short)lb, (short)lc, (short)ld};
    *(s16x4*)(Lh + pix * 40 + c4 * 4) = vh;
    *(s16x4*)(Ll + pix * 40 + c4 * 4) = vl;
  }
  __syncthreads();
  int wv = tid >> 6, lane = tid & 63;
  int lr = lane & 15, lhi = lane >> 4;
  int nt = wv & 1, mrow0 = (wv >> 1) * 8;
  bf16x8 wh[9], wl[9];
#pragma unroll
  for (int tap = 0; tap < 9; ++tap) {
    int base = ((tap * 2 + nt) * 64 + lane) * 8;
    wh[tap] = *(const bf16x8*)(Wch + base);
    wl[tap] = *(const bf16x8*)(Wcl + base);
  }
  f32x4 acc[8];
#pragma unroll
  for (int mt = 0; mt < 8; ++mt) acc[mt] = (f32x4){0.f, 0.f, 0.f, 0.f};
#pragma unroll
  for (int mt = 0; mt < 8; ++mt) {
    int row = mrow0 + mt;
#pragma unroll
    for (int tap = 0; tap < 9; ++tap) {
      int dy = tap / 3, dx = tap - dy * 3;
      int pixel = (row + dy) * 18 + (lr + dx);
      bf16x8 ah = *(const bf16x8*)(Lh + pixel * 40 + lhi * 8);
      bf16x8 al = *(const bf16x8*)(Ll + pixel * 40 + lhi * 8);
      acc[mt] = __builtin_amdgcn_mfma_f32_16x16x32_bf16(ah, wh[tap], acc[mt], 0, 0, 0);
      acc[mt] = __builtin_amdgcn_mfma_f32_16x16x32_bf16(ah, wl[tap], acc[mt], 0, 0, 0);
      acc[mt] = __builtin_amdgcn_mfma_f32_16x16x32_bf16(al, wh[tap], acc[mt], 0, 0, 0);
    }
  }
  int co = nt * 16 + lr;
  float bv = bias[co];
#pragma unroll
  for (int a = 0; a < 4; ++a) {
#pragma unroll
    for (int bb = 0; bb < 2; ++bb) {
      float v00 = fmaxf(acc[2 * a][2 * bb] + bv, 0.f);
      float v01 = fmaxf(acc[2 * a][2 * bb + 1] + bv, 0.f);
      float v10 = fmaxf(acc[2 * a + 1][2 * bb] + bv, 0.f);
      float v11 = fmaxf(acc[2 * a + 1][2 * bb + 1] + bv, 0.f);
      float p = fmaxf(fmaxf(v00, v01), fmaxf(v10, v11));
      int gy = (tY >> 1) + (mrow0 >> 1) + a;
      int gx = (tX >> 1) + lhi * 2 + bb;
      if (gy < 18 && gx < 18)
        h2[(((size_t)b * 18 + gy) * 18 + gx) * 32 + co] = p;
    }
  }
}

// ---------------- K3a: dense partial GEMM (K-split, MFMA split-bf16) -------
__global__ __launch_bounds__(256) void k_dense_part(
    const float* __restrict__ h2, const float* __restrict__ w,
    float* __restrict__ part) {
  __shared__ __align__(16) unsigned short Ah[128 * 40];
  __shared__ __align__(16) unsigned short Al[128 * 40];
  __shared__ __align__(16) unsigned short Bh[64 * 40];
  __shared__ __align__(16) unsigned short Bl[64 * 40];
  int tid = threadIdx.x;
  int n0 = blockIdx.x * 64;   // 14 blocks (last ragged)
  int kc = blockIdx.y;        // 18 K-chunks of 576
  int wv = tid >> 6, lane = tid & 63;
  int lr = lane & 15, lhi = lane >> 4;
  f32x4 acc[8];
#pragma unroll
  for (int m = 0; m < 8; ++m) acc[m] = (f32x4){0.f, 0.f, 0.f, 0.f};
  for (int kt = 0; kt < 18; ++kt) {
    int kb = kc * 576 + kt * 32;
    if (kt) __syncthreads();
#pragma unroll
    for (int it = 0; it < 4; ++it) {
      int f = tid + it * 256;  // 0..1023 : 128 m rows x 8 float4
      int ml = f >> 3, kq = f & 7;
      float4 p = *(const float4*)(h2 + (size_t)ml * 10368 + kb + kq * 4);
      unsigned short h0, l0, h1, l1, h2_, l2_, h3, l3;
      split2t(p.x, h0, l0); split2t(p.y, h1, l1);
      split2t(p.z, h2_, l2_); split2t(p.w, h3, l3);
      s16x4 vh = {(short)h0, (short)h1, (short)h2_, (short)h3};
      s16x4 vl = {(short)l0, (short)l1, (short)l2_, (short)l3};
      *(s16x4*)(Ah + ml * 40 + kq * 4) = vh;
      *(s16x4*)(Al + ml * 40 + kq * 4) = vl;
    }
#pragma unroll
    for (int it = 0; it < 2; ++it) {
      int f = tid + it * 256;  // 0..511 : 32 k rows x 16 float4
      int kr = f >> 4, n4 = (f & 15) * 4;
      float4 p = {0.f, 0.f, 0.f, 0.f};
      if (n0 + n4 < 864)
        p = *(const float4*)(w + (size_t)(kb + kr) * 864 + n0 + n4);
      unsigned short hh, ll;
      split2t(p.x, hh, ll); Bh[(n4 + 0) * 40 + kr] = hh; Bl[(n4 + 0) * 40 + kr] = ll;
      split2t(p.y, hh, ll); Bh[(n4 + 1) * 40 + kr] = hh; Bl[(n4 + 1) * 40 + kr] = ll;
      split2t(p.z, hh, ll); Bh[(n4 + 2) * 40 + kr] = hh; Bl[(n4 + 2) * 40 + kr] = ll;
      split2t(p.w, hh, ll); Bh[(n4 + 3) * 40 + kr] = hh; Bl[(n4 + 3) * 40 + kr] = ll;
    }
    __syncthreads();
    bf16x8 bh_ = *(const bf16x8*)(Bh + (wv * 16 + lr) * 40 + lhi * 8);
    bf16x8 bl_ = *(const bf16x8*)(Bl + (wv * 16 + lr) * 40 + lhi * 8);
#pragma unroll
    for (int m = 0; m < 8; ++m) {
      bf16x8 ah = *(const bf16x8*)(Ah + (m * 16 + lr) * 40 + lhi * 8);
      bf16x8 al = *(const bf16x8*)(Al + (m * 16 + lr) * 40 + lhi * 8);
      acc[m] = __builtin_amdgcn_mfma_f32_16x16x32_bf16(ah, bh_, acc[m], 0, 0, 0);
      acc[m] = __builtin_amdgcn_mfma_f32_16x16x32_bf16(ah, bl_, acc[m], 0, 0, 0);
      acc[m] = __builtin_amdgcn_mfma_f32_16x16x32_bf16(al, bh_, acc[m], 0, 0, 0);
    }
  }
  int n = n0 + wv * 16 + lr;
  if (n < 864) {
#pragma unroll
    for (int m = 0; m < 8; ++m) {
#pragma unroll
      for (int r = 0; r < 4; ++r) {
        int mm = m * 16 + lhi * 4 + r;
        part[((size_t)kc * 128 + mm) * 864 + n] = acc[m][r];
      }
    }
  }
}

// ---------------- K_finprep: reduce partials -> filt (LDS) -> W1eff frags --
__global__ __launch_bounds__(256) void k_finprep(
    const float* __restrict__ part, const float* __restrict__ bias,
    const float* __restrict__ W1,
    unsigned short* __restrict__ Eh, unsigned short* __restrict__ El) {
  __shared__ float fl[864];
  int b = blockIdx.x;
  int tid = threadIdx.x;
  for (int e = tid; e < 864; e += 256) {
    float s = bias[e];
#pragma unroll
    for (int kc = 0; kc < 18; ++kc) s += part[(size_t)kc * 110592 + b * 864 + e];
    fl[e] = fmaxf(s, 0.f);
  }
  __syncthreads();
  int col = tid & 127;
  int k0 = tid >> 7;
  for (int k = k0; k < 64; k += 2) {
    float v;
    if (k < 12) {
      v = W1[k * 128 + col];
    } else if (k < 48) {
      int h = (k - 12) / 3, t = (k - 12) % 3;
      const float* wp = W1 + (12 + t) * 128 + col;  // + c*384 walks rows 12+3c+t
      const float* fp = fl + h * 72;
      float a0 = 0.f, a1 = 0.f, a2 = 0.f, a3 = 0.f;
      for (int c = 0; c < 72; c += 4) {
        a0 = fmaf(fp[c], wp[(size_t)c * 384], a0);
        a1 = fmaf(fp[c + 1], wp[(size_t)(c + 1) * 384], a1);
        a2 = fmaf(fp[c + 2], wp[(size_t)(c + 2) * 384], a2);
        a3 = fmaf(fp[c + 3], wp[(size_t)(c + 3) * 384], a3);
      }
      v = (a0 + a1) + (a2 + a3);
    } else {
      v = 0.f;
    }
    unsigned short hh, ll;
    split2(v, hh, ll);
    int ks = k >> 5, j = k & 7, a4 = (k >> 3) & 3;
    int l = a4 * 16 + (col & 15), nt = col >> 4;
    size_t o = (((size_t)b * 8 + nt) * 2 + ks) * 512 + l * 8 + j;
    Eh[o] = hh;
    El[o] = ll;
  }
}

// ---------------- K4: fused CA update (halved u-exchange, 5 blocks/CU) -----
__global__ __launch_bounds__(256, 5) void k_ca(
    const float* __restrict__ x,
    const unsigned short* __restrict__ Eh, const unsigned short* __restrict__ El,
    const float* __restrict__ B1,
    const unsigned short* __restrict__ W2h, const unsigned short* __restrict__ W2l,
    const float* __restrict__ B2,
    float* __restrict__ xnew, float* __restrict__ aold,
    float* __restrict__ anew) {
  // staging: ia [16][120] f32 @0 (7680) | PAh @7680 (9216) | PAl @16896 (9216)
  // -> 26112. Union after main GEMM: U32 @0 [64 px][68] u32 (17408) holds ONE
  // 64-hid half of u at a time. mskL @26112 (256). Total 26368 -> 5 blk/CU.
  __shared__ __align__(16) unsigned char S[26368];
  float* ia = (float*)S;
  unsigned short* PAh = (unsigned short*)(S + 7680);
  unsigned short* PAl = (unsigned short*)(S + 16896);
  unsigned* U32 = (unsigned*)S;
  float* mskL = (float*)(S + 26112);

  int tid = threadIdx.x;
  int b = blockIdx.y;
  int tx = (blockIdx.x & 7) * 8, ty = (blockIdx.x >> 3) * 8;
  int wv = tid >> 6, lane = tid & 63;
  int lr = lane & 15, lhi = lane >> 4;

  // prefetch W1eff B-frags (global, hides under phase A)
  bf16x8 bh[2][2], bl[2][2];
#pragma unroll
  for (int nt = 0; nt < 2; ++nt)
#pragma unroll
    for (int ks = 0; ks < 2; ++ks) {
      size_t base = (((size_t)b * 8 + (wv * 2 + nt)) * 2 + ks) * 512 + lane * 8;
      bh[nt][ks] = *(const bf16x8*)(Eh + base);
      bl[nt][ks] = *(const bf16x8*)(El + base);
    }
  // prefetch xo for phase D: px = wv*16 + lhi*4 + r, channel lr
  float xo[4];
#pragma unroll
  for (int r = 0; r < 4; ++r) {
    int px = wv * 16 + lhi * 4 + r;
    int gy = ty + (px >> 3), gx = tx + (px & 7);
    xo[r] = x[(((size_t)b * 64 + gy) * 64 + gx) * 16 + lr];
  }

  // ---- phase A: x halo -> ia; threefry -> mskL; zero PA k-pad 48..63
  if (tid < 200) {
    int px_ = tid >> 1, half = tid & 1;
    int hy = px_ / 10, hx = px_ - hy * 10;
    int pp = hy * 12 + hx;
    int gy = ty + hy - 1, gx = tx + hx - 1;
    float4 v0 = {0.f, 0.f, 0.f, 0.f}, v1 = {0.f, 0.f, 0.f, 0.f};
    if (gy >= 0 && gy < 64 && gx >= 0 && gx < 64) {
      const float* xp = x + (((size_t)b * 64 + gy) * 64 + gx) * 16 + half * 8;
      v0 = *(const float4*)xp;
      v1 = *(const float4*)(xp + 4);
    }
    int c0 = half * 8;
    ia[(c0 + 0) * 120 + pp] = v0.x; ia[(c0 + 1) * 120 + pp] = v0.y;
    ia[(c0 + 2) * 120 + pp] = v0.z; ia[(c0 + 3) * 120 + pp] = v0.w;
    ia[(c0 + 4) * 120 + pp] = v1.x; ia[(c0 + 5) * 120 + pp] = v1.y;
    ia[(c0 + 6) * 120 + pp] = v1.z; ia[(c0 + 7) * 120 + pp] = v1.w;
  }
  {
    if (tid >= 192) {
      int p = tid - 192;
      int gy = ty + (p >> 3), gx = tx + (p & 7);
      unsigned pix = (unsigned)(b * 4096 + gy * 64 + gx);
      mskL[p] = (tf42_uniform(pix) <= 0.5f) ? 1.f : 0.f;
    }
    const s16x4 z4 = {0, 0, 0, 0};
    if (wv == 2) {
#pragma unroll
      for (int g = 0; g < 4; ++g) *(s16x4*)(PAh + lane * 72 + 48 + 4 * g) = z4;
    }
    if (wv == 3) {
#pragma unroll
      for (int g = 0; g < 4; ++g) *(s16x4*)(PAl + lane * 72 + 48 + 4 * g) = z4;
    }
  }
  __syncthreads();

  // ---- phase P: perception of ch 4wv..4wv+3 -> PA cols 12wv..12wv+11
  {
    int py = lane >> 3, pxx = lane & 7;
    const float* pc0 = ia + (py + 1) * 12 + (pxx + 1);
    unsigned short oh[12], ol[12];
#pragma unroll
    for (int i = 0; i < 4; ++i) {
      const float* pc = pc0 + (wv * 4 + i) * 120;
      float n00 = pc[-13], n01 = pc[-12], n02 = pc[-11];
      float n10 = pc[-1],  n11 = pc[0],   n12 = pc[1];
      float n20 = pc[11],  n21 = pc[12],  n22 = pc[13];
      float pid = n11;
      float psx = ((n02 - n00) + 2.f * (n12 - n10) + (n22 - n20)) * 0.125f;
      float psy = ((n20 - n00) + 2.f * (n21 - n01) + (n22 - n02)) * 0.125f;
      split2t(pid, oh[3 * i + 0], ol[3 * i + 0]);
      split2t(psx, oh[3 * i + 1], ol[3 * i + 1]);
      split2t(psy, oh[3 * i + 2], ol[3 * i + 2]);
    }
    int off = lane * 72 + wv * 12;
#pragma unroll
    for (int g = 0; g < 3; ++g) {
      s16x4 vh = {(short)oh[4 * g], (short)oh[4 * g + 1],
                  (short)oh[4 * g + 2], (short)oh[4 * g + 3]};
      s16x4 vl = {(short)ol[4 * g], (short)ol[4 * g + 1],
                  (short)ol[4 * g + 2], (short)ol[4 * g + 3]};
      *(s16x4*)(PAh + off + 4 * g) = vh;
      *(s16x4*)(PAl + off + 4 * g) = vl;
    }
  }
  __syncthreads();

  // ---- phase M: main GEMM, 2 ks x 4 m x 2 nt x 3 passes
  f32x4 acc[4][2];
#pragma unroll
  for (int m = 0; m < 4; ++m)
#pragma unroll
    for (int nt = 0; nt < 2; ++nt)
      acc[m][nt] = (f32x4){0.f, 0.f, 0.f, 0.f};
#pragma unroll
  for (int ks = 0; ks < 2; ++ks) {
#pragma unroll
    for (int m = 0; m < 4; ++m) {
      int arow = m * 16 + lr;
      bf16x8 pah = *(const bf16x8*)(PAh + arow * 72 + ks * 32 + lhi * 8);
      bf16x8 pal = *(const bf16x8*)(PAl + arow * 72 + ks * 32 + lhi * 8);
#pragma unroll
      for (int nt = 0; nt < 2; ++nt) {
        acc[m][nt] = __builtin_amdgcn_mfma_f32_16x16x32_bf16(
            pah, bh[nt][ks], acc[m][nt], 0, 0, 0);
        acc[m][nt] = __builtin_amdgcn_mfma_f32_16x16x32_bf16(
            pah, bl[nt][ks], acc[m][nt], 0, 0, 0);
        acc[m][nt] = __builtin_amdgcn_mfma_f32_16x16x32_bf16(
            pal, bh[nt][ks], acc[m][nt], 0, 0, 0);
      }
    }
  }
  // prefetch W2 frags (consumed after next barrier)
  bf16x8 ch_[4], cl_[4];
#pragma unroll
  for (int ks = 0; ks < 4; ++ks) {
    ch_[ks] = *(const bf16x8*)(W2h + ks * 512 + lane * 8);
    cl_[ks] = *(const bf16x8*)(W2l + ks * 512 + lane * 8);
  }

  // ---- halved u-exchange + dx MFMA: two 64-hid halves through U32[64][68]
  // wave wv owns hid d0 = wv*32 (half h = wv>>1, local base = (wv&1)*32).
  int d0 = wv * 32;
  float b1v0 = B1[d0 + lr], b1v1 = B1[d0 + 16 + lr];
  union Cvt { unsigned d[4]; bf16x8 v8; };
  f32x4 acc2 = {0.f, 0.f, 0.f, 0.f};
  const unsigned* urow = U32 + (wv * 16 + lr) * 68;
#pragma unroll
  for (int h = 0; h < 2; ++h) {
    __syncthreads();  // h=0: PA dead; h=1: half-0 reads done
    if ((wv >> 1) == h) {
      int hidloc = (wv & 1) * 32 + lr;
#pragma unroll
      for (int m = 0; m < 4; ++m)
#pragma unroll
        for (int nt = 0; nt < 2; ++nt) {
          float bv = nt ? b1v1 : b1v0;
#pragma unroll
          for (int r = 0; r < 4; ++r) {
            int px = m * 16 + lhi * 4 + r;
            U32[px * 68 + hidloc + nt * 16] =
                pack_bf2(fmaxf(acc[m][nt][r] + bv, 0.f));
          }
        }
    }
    __syncthreads();
#pragma unroll
    for (int ksl = 0; ksl < 2; ++ksl) {
      int ks = h * 2 + ksl;
      u32x4 q0 = *(const u32x4*)(urow + ksl * 32 + lhi * 8);
      u32x4 q1 = *(const u32x4*)(urow + ksl * 32 + lhi * 8 + 4);
      Cvt ah, al;
#pragma unroll
      for (int i = 0; i < 2; ++i) {
        unsigned p0 = q0[2 * i], p1 = q0[2 * i + 1];
        ah.d[i] = (p0 & 0xffffu) | (p1 << 16);
        al.d[i] = (p0 >> 16) | (p1 & 0xffff0000u);
      }
#pragma unroll
      for (int i = 0; i < 2; ++i) {
        unsigned p0 = q1[2 * i], p1 = q1[2 * i + 1];
        ah.d[2 + i] = (p0 & 0xffffu) | (p1 << 16);
        al.d[2 + i] = (p0 >> 16) | (p1 & 0xffff0000u);
      }
      acc2 = __builtin_amdgcn_mfma_f32_16x16x32_bf16(ah.v8, ch_[ks], acc2, 0, 0, 0);
      acc2 = __builtin_amdgcn_mfma_f32_16x16x32_bf16(ah.v8, cl_[ks], acc2, 0, 0, 0);
      acc2 = __builtin_amdgcn_mfma_f32_16x16x32_bf16(al.v8, ch_[ks], acc2, 0, 0, 0);
    }
  }

  // ---- phase D: dx + fire mask + write x_new + alphas (lane holds e=lr)
  float b2v = B2[lr];
#pragma unroll
  for (int r = 0; r < 4; ++r) {
    int px = wv * 16 + lhi * 4 + r;
    int gy = ty + (px >> 3), gx = tx + (px & 7);
    float m_ = mskL[px];
    float xn = xo[r] + (acc2[r] + b2v) * m_;
    size_t o = (((size_t)b * 64 + gy) * 64 + gx) * 16 + lr;
    xnew[o] = xn;
    if (lr == 3) {
      unsigned pix = (unsigned)(b * 4096 + gy * 64 + gx);
      aold[pix] = xo[r];
      anew[pix] = xn;
    }
  }
}

// ---------------- K5: living mask; ZERO only dead pixels (in place) --------
__global__ __launch_bounds__(256) void k_final(
    float* __restrict__ xnew, const float* __restrict__ aold,
    const float* __restrict__ anew) {
  int t = blockIdx.x * 256 + threadIdx.x;  // grid 2048*256 = 524288
  int gx = t & 63, gy = (t >> 6) & 63, b = t >> 12;
  float mo = -1e30f, mn = -1e30f;
  for (int dy = -1; dy <= 1; ++dy) {
    int yy = gy + dy; if (yy < 0 || yy >= 64) continue;
    for (int dx = -1; dx <= 1; ++dx) {
      int xx = gx + dx; if (xx < 0 || xx >= 64) continue;
      int p = b * 4096 + yy * 64 + xx;
      mo = fmaxf(mo, aold[p]);
      mn = fmaxf(mn, anew[p]);
    }
  }
  if (!(mo > 0.1f && mn > 0.1f)) {
    size_t base = (size_t)t * 16;
    const float4 z = {0.f, 0.f, 0.f, 0.f};
#pragma unroll
    for (int c4 = 0; c4 < 4; ++c4)
      *(float4*)(xnew + base + c4 * 4) = z;
  }
}

// ---------------- launch ----------------
extern "C" void kernel_launch(void* const* d_in, const int* in_sizes, int n_in,
                              void* d_out, int out_size, void* d_ws, size_t ws_size,
                              hipStream_t stream) {
  const float* x    = (const float*)d_in[0];
  const float* img  = (const float*)d_in[1];
  const float* g1   = (const float*)d_in[2];
  const float* be1  = (const float*)d_in[3];
  const float* m1   = (const float*)d_in[4];
  const float* v1   = (const float*)d_in[5];
  const float* w1c  = (const float*)d_in[6];
  const float* b1c  = (const float*)d_in[7];
  const float* g2   = (const float*)d_in[8];
  const float* be2  = (const float*)d_in[9];
  const float* m2   = (const float*)d_in[10];
  const float* v2   = (const float*)d_in[11];
  const float* w2c  = (const float*)d_in[12];
  const float* b2c  = (const float*)d_in[13];
  const float* dw   = (const float*)d_in[14];
  const float* db   = (const float*)d_in[15];
  const float* uw1  = (const float*)d_in[16];
  const float* ub1  = (const float*)d_in[17];
  const float* uw2  = (const float*)d_in[18];
  const float* ub2  = (const float*)d_in[19];

  char* ws = (char*)d_ws;
  float* h1   = (float*)(ws);                        // 21,233,664 B (dead after conv2)
  float* part = h1;                                  // aliased (written by dense)
  float* h2   = (float*)(ws + 21233664);             // 5,308,416 B
  float* aold = (float*)(ws + 26542080);             // 2,097,152 B
  float* anew = (float*)(ws + 28639232);             // 2,097,152 B
  unsigned short* W2Bh = (unsigned short*)(ws + 30736384);  // 4,096 B
  unsigned short* W2Bl = (unsigned short*)(ws + 30740480);  // 4,096 B
  unsigned short* Wc2h = (unsigned short*)(ws + 30744576);  // 18,432 B
  unsigned short* Wc2l = (unsigned short*)(ws + 30763008);  // 18,432 B
  unsigned short* Wc1h = (unsigned short*)(ws + 30781440);  // 6,144 B
  unsigned short* Wc1l = (unsigned short*)(ws + 30787584);  // 6,144 B
  unsigned short* W1Eh = (unsigned short*)(ws + 30793728);  // 2,097,152 B
  unsigned short* W1El = (unsigned short*)(ws + 32890880);  // 2,097,152 B
  // total 34,988,032 B
  float* xnew = (float*)d_out;                       // (128,64,64,16) f32

  k_prep_w<<<49, 256, 0, stream>>>(w1c, w2c, uw2, Wc1h, Wc1l, Wc2h, Wc2l,
                                   W2Bh, W2Bl);
  k_conv1<<<dim3(25, 128), 256, 0, stream>>>(img, g1, be1, m1, v1, Wc1h, Wc1l,
                                             b1c, g2, be2, m2, v2, h1);
  k_conv2<<<dim3(9, 128), 256, 0, stream>>>(h1, Wc2h, Wc2l, b2c, h2);
  k_dense_part<<<dim3(14, 18), 256, 0, stream>>>(h2, dw, part);
  k_finprep<<<128, 256, 0, stream>>>(part, db, uw1, W1Eh, W1El);
  k_ca<<<dim3(64, 128), 256, 0, stream>>>(x, W1Eh, W1El, ub1, W2Bh, W2Bl, ub2,
                                          xnew, aold, anew);
  k_final<<<2048, 256, 0, stream>>>(xnew, aold, anew);
}

// Round 19
// 167.220 us; speedup vs baseline: 1.2011x; 1.0422x over previous
//
#include <hip/hip_runtime.h>

#define BN_EPS 1e-3f

typedef __attribute__((ext_vector_type(8))) short bf16x8;
typedef __attribute__((ext_vector_type(4))) short s16x4;
typedef __attribute__((ext_vector_type(4))) float f32x4;
typedef __attribute__((ext_vector_type(4))) unsigned u32x4;

// ---------------- bf16 split helpers ----------------
__device__ __forceinline__ unsigned short f2bf_rne(float f) {
  unsigned u = __float_as_uint(f);
  unsigned r = u + 0x7fffu + ((u >> 16) & 1u);
  return (unsigned short)(r >> 16);
}
__device__ __forceinline__ float bf2f(unsigned short h) {
  return __uint_as_float(((unsigned)h) << 16);
}
__device__ __forceinline__ void split2(float v, unsigned short& h, unsigned short& l) {
  h = f2bf_rne(v);
  l = f2bf_rne(v - bf2f(h));
}
// cheaper exact split: hi = truncated bf16 (bit AND), lo = RNE(v - hi).
__device__ __forceinline__ void split2t(float v, unsigned short& h, unsigned short& l) {
  unsigned u = __float_as_uint(v);
  float hi = __uint_as_float(u & 0xFFFF0000u);
  h = (unsigned short)(u >> 16);
  l = f2bf_rne(v - hi);
}
// packed split: returns (hi_trunc) | (lo_rne << 16) in one u32.
__device__ __forceinline__ unsigned pack_bf2(float v) {
  unsigned u = __float_as_uint(v);
  float lof = v - __uint_as_float(u & 0xFFFF0000u);
  unsigned lb = __float_as_uint(lof);
  unsigned rr = lb + 0x7fffu + ((lb >> 16) & 1u);
  return (u >> 16) | (rr & 0xFFFF0000u);
}

// ---------------- threefry2x32 (JAX partitionable path, key=[0,42]) --------
__device__ __forceinline__ unsigned rotl32(unsigned v, int n) {
  return (v << n) | (v >> (32 - n));
}

__device__ __forceinline__ float tf42_uniform(unsigned i) {
  unsigned x0 = 0u, x1 = i;
  const unsigned k0 = 0u, k1 = 42u, k2 = 0u ^ 42u ^ 0x1BD11BDAu;
  x0 += k0; x1 += k1;
#define TFR(r) { x0 += x1; x1 = rotl32(x1, r); x1 ^= x0; }
  TFR(13) TFR(15) TFR(26) TFR(6)
  x0 += k1; x1 += k2 + 1u;
  TFR(17) TFR(29) TFR(16) TFR(24)
  x0 += k2; x1 += k0 + 2u;
  TFR(13) TFR(15) TFR(26) TFR(6)
  x0 += k0; x1 += k1 + 3u;
  TFR(17) TFR(29) TFR(16) TFR(24)
  x0 += k1; x1 += k2 + 4u;
  TFR(13) TFR(15) TFR(26) TFR(6)
  x0 += k2; x1 += k0 + 5u;
#undef TFR
  unsigned bits = x0 ^ x1;
  return __uint_as_float((bits >> 9) | 0x3F800000u) - 1.0f;
}

// ---------------- K_prep_w: all static weight frags in one launch ----------
// blk 0..11: conv1 (3,3,4,32) -> [ks 3][nt 2][lane 64][8], invalid K -> 0
// blk 12..47: conv2 (3,3,32,32) -> [tap 9][nt 2][lane 64][8]
// blk 48: W2 (128,16) -> [ks 4][lane 64][8]
__global__ __launch_bounds__(256) void k_prep_w(
    const float* __restrict__ w1, const float* __restrict__ w2,
    const float* __restrict__ W2d,
    unsigned short* __restrict__ W1h, unsigned short* __restrict__ W1l,
    unsigned short* __restrict__ W2h_, unsigned short* __restrict__ W2l_,
    unsigned short* __restrict__ WD2h, unsigned short* __restrict__ WD2l) {
  int blk = blockIdx.x, tid = threadIdx.x;
  if (blk < 12) {
    int t = blk * 256 + tid;
    int j = t & 7, l = (t >> 3) & 63, nt = (t >> 9) & 1, ks = t >> 10;
    int k = 32 * ks + ((l >> 4) << 3) + j;
    int tap = k >> 3, ci = k & 7;
    float v = (tap < 9 && ci < 4) ? w1[tap * 128 + ci * 32 + nt * 16 + (l & 15)] : 0.f;
    unsigned short hh, ll; split2(v, hh, ll);
    W1h[t] = hh; W1l[t] = ll;
  } else if (blk < 48) {
    int t = (blk - 12) * 256 + tid;
    int j = t & 7, l = (t >> 3) & 63, nt = (t >> 9) & 1, tap = t >> 10;
    int ci = ((l >> 4) << 3) + j, co = nt * 16 + (l & 15);
    float v = w2[tap * 1024 + ci * 32 + co];
    unsigned short hh, ll; split2(v, hh, ll);
    W2h_[t] = hh; W2l_[t] = ll;
  } else {
    for (int t = tid; t < 2048; t += 256) {
      int j = t & 7, l = (t >> 3) & 63, ks = t >> 9;
      int k = 32 * ks + ((l >> 4) << 3) + j;
      int col = l & 15;
      float v = W2d[k * 16 + col];
      unsigned short hh, ll; split2(v, hh, ll);
      WD2h[t] = hh; WD2l[t] = ll;
    }
  }
}

// ---------------- K1: bn1 + conv1(4->32) + relu + maxpool2 + bn2 (MFMA) ----
__global__ __launch_bounds__(256) void k_conv1(
    const float* __restrict__ img,
    const float* __restrict__ g1, const float* __restrict__ be1,
    const float* __restrict__ m1, const float* __restrict__ v1,
    const unsigned short* __restrict__ Wc1h, const unsigned short* __restrict__ Wc1l,
    const float* __restrict__ bias,
    const float* __restrict__ g2, const float* __restrict__ be2,
    const float* __restrict__ m2, const float* __restrict__ v2,
    float* __restrict__ h1) {
  __shared__ __align__(16) unsigned short Lh[2592];  // 324 px * 8
  __shared__ __align__(16) unsigned short Ll[2592];
  int tid = threadIdx.x;
  int b = blockIdx.y;
  int tY = (blockIdx.x / 5) * 16, tX = (blockIdx.x % 5) * 16;
  float s1[4], t1[4];
#pragma unroll
  for (int ci = 0; ci < 4; ++ci) {
    float s = g1[ci] / sqrtf(v1[ci] + BN_EPS);
    s1[ci] = s; t1[ci] = be1[ci] - m1[ci] * s;
  }
  const s16x4 z4 = {0, 0, 0, 0};
  for (int idx = tid; idx < 324; idx += 256) {
    int ly = idx / 18, lx = idx - ly * 18;
    int gy = tY - 1 + ly, gx = tX - 1 + lx;
    float4 v = {0.f, 0.f, 0.f, 0.f};
    if (gy >= 0 && gy < 72 && gx >= 0 && gx < 72) {
      v = *(const float4*)(img + (((size_t)b * 72 + gy) * 72 + gx) * 4);
      v.x = v.x * s1[0] + t1[0];
      v.y = v.y * s1[1] + t1[1];
      v.z = v.z * s1[2] + t1[2];
      v.w = v.w * s1[3] + t1[3];
    }
    unsigned short ha, la, hb, lb, hc, lc, hd, ld;
    split2t(v.x, ha, la); split2t(v.y, hb, lb);
    split2t(v.z, hc, lc); split2t(v.w, hd, ld);
    s16x4 vh = {(short)ha, (short)hb, (short)hc, (short)hd};
    s16x4 vl = {(short)la, (short)lb, (short)lc, (short)ld};
    *(s16x4*)(Lh + idx * 8) = vh;
    *(s16x4*)(Lh + idx * 8 + 4) = z4;
    *(s16x4*)(Ll + idx * 8) = vl;
    *(s16x4*)(Ll + idx * 8 + 4) = z4;
  }
  __syncthreads();
  int wv = tid >> 6, lane = tid & 63;
  int lr = lane & 15, lhi = lane >> 4;
  int nt = wv & 1, mrow0 = (wv >> 1) * 8;
  bf16x8 wh[3], wl[3];
#pragma unroll
  for (int ks = 0; ks < 3; ++ks) {
    int base = ((ks * 2 + nt) * 64 + lane) * 8;
    wh[ks] = *(const bf16x8*)(Wc1h + base);
    wl[ks] = *(const bf16x8*)(Wc1l + base);
  }
  f32x4 acc[8];
#pragma unroll
  for (int mt = 0; mt < 8; ++mt) acc[mt] = (f32x4){0.f, 0.f, 0.f, 0.f};
#pragma unroll
  for (int ks = 0; ks < 3; ++ks) {
    int tap = 4 * ks + lhi;
    int tc = tap > 8 ? 8 : tap;  // invalid taps have B == 0
    int dy = tc / 3, dx = tc - 3 * dy;
#pragma unroll
    for (int mt = 0; mt < 8; ++mt) {
      int row = mrow0 + mt;
      int px = (row + dy) * 18 + lr + dx;
      bf16x8 ah = *(const bf16x8*)(Lh + px * 8);
      bf16x8 al = *(const bf16x8*)(Ll + px * 8);
      acc[mt] = __builtin_amdgcn_mfma_f32_16x16x32_bf16(ah, wh[ks], acc[mt], 0, 0, 0);
      acc[mt] = __builtin_amdgcn_mfma_f32_16x16x32_bf16(ah, wl[ks], acc[mt], 0, 0, 0);
      acc[mt] = __builtin_amdgcn_mfma_f32_16x16x32_bf16(al, wh[ks], acc[mt], 0, 0, 0);
    }
  }
  int co = nt * 16 + lr;
  float bv = bias[co];
  float s2 = g2[co] / sqrtf(v2[co] + BN_EPS);
  float t2 = be2[co] - m2[co] * s2;
#pragma unroll
  for (int a = 0; a < 4; ++a) {
#pragma unroll
    for (int bb = 0; bb < 2; ++bb) {
      float v00 = fmaxf(acc[2 * a][2 * bb] + bv, 0.f);
      float v01 = fmaxf(acc[2 * a][2 * bb + 1] + bv, 0.f);
      float v10 = fmaxf(acc[2 * a + 1][2 * bb] + bv, 0.f);
      float v11 = fmaxf(acc[2 * a + 1][2 * bb + 1] + bv, 0.f);
      float p = fmaxf(fmaxf(v00, v01), fmaxf(v10, v11));
      int gy = (tY >> 1) + (mrow0 >> 1) + a;
      int gx = (tX >> 1) + lhi * 2 + bb;
      if (gy < 36 && gx < 36)
        h1[(((size_t)b * 36 + gy) * 36 + gx) * 32 + co] = p * s2 + t2;
    }
  }
}

// ---------------- K2: conv2(32->32) + relu + maxpool2 (MFMA) ---------------
__global__ __launch_bounds__(256, 3) void k_conv2(
    const float* __restrict__ hin,
    const unsigned short* __restrict__ Wch, const unsigned short* __restrict__ Wcl,
    const float* __restrict__ bias, float* __restrict__ h2) {
  __shared__ __align__(16) unsigned short Lh[12960];  // 324 px * 40
  __shared__ __align__(16) unsigned short Ll[12960];
  int tid = threadIdx.x;
  int b = blockIdx.y;
  int tY = (blockIdx.x / 3) * 16, tX = (blockIdx.x % 3) * 16;
  for (int idx = tid; idx < 2592; idx += 256) {
    int pix = idx >> 3, c4 = idx & 7;
    int ly = pix / 18, lx = pix - ly * 18;
    int gy = tY - 1 + ly, gx = tX - 1 + lx;
    float4 v = {0.f, 0.f, 0.f, 0.f};
    if (gy >= 0 && gy < 36 && gx >= 0 && gx < 36)
      v = *(const float4*)(hin + (((size_t)b * 36 + gy) * 36 + gx) * 32 + c4 * 4);
    unsigned short ha, la, hb, lb, hc, lc, hd, ld;
    split2t(v.x, ha, la); split2t(v.y, hb, lb);
    split2t(v.z, hc, lc); split2t(v.w, hd, ld);
    s16x4 vh = {(short)ha, (short)hb, (short)hc, (short)hd};
    s16x4 vl = {(short)la, (short)lb, (short)lc, (short)ld};
    *(s16x4*)(Lh + pix * 40 + c4 * 4) = vh;
    *(s16x4*)(Ll + pix * 40 + c4 * 4) = vl;
  }
  __syncthreads();
  int wv = tid >> 6, lane = tid & 63;
  int lr = lane & 15, lhi = lane >> 4;
  int nt = wv & 1, mrow0 = (wv >> 1) * 8;
  bf16x8 wh[9], wl[9];
#pragma unroll
  for (int tap = 0; tap < 9; ++tap) {
    int base = ((tap * 2 + nt) * 64 + lane) * 8;
    wh[tap] = *(const bf16x8*)(Wch + base);
    wl[tap] = *(const bf16x8*)(Wcl + base);
  }
  f32x4 acc[8];
#pragma unroll
  for (int mt = 0; mt < 8; ++mt) acc[mt] = (f32x4){0.f, 0.f, 0.f, 0.f};
#pragma unroll
  for (int mt = 0; mt < 8; ++mt) {
    int row = mrow0 + mt;
#pragma unroll
    for (int tap = 0; tap < 9; ++tap) {
      int dy = tap / 3, dx = tap - dy * 3;
      int pixel = (row + dy) * 18 + (lr + dx);
      bf16x8 ah = *(const bf16x8*)(Lh + pixel * 40 + lhi * 8);
      bf16x8 al = *(const bf16x8*)(Ll + pixel * 40 + lhi * 8);
      acc[mt] = __builtin_amdgcn_mfma_f32_16x16x32_bf16(ah, wh[tap], acc[mt], 0, 0, 0);
      acc[mt] = __builtin_amdgcn_mfma_f32_16x16x32_bf16(ah, wl[tap], acc[mt], 0, 0, 0);
      acc[mt] = __builtin_amdgcn_mfma_f32_16x16x32_bf16(al, wh[tap], acc[mt], 0, 0, 0);
    }
  }
  int co = nt * 16 + lr;
  float bv = bias[co];
#pragma unroll
  for (int a = 0; a < 4; ++a) {
#pragma unroll
    for (int bb = 0; bb < 2; ++bb) {
      float v00 = fmaxf(acc[2 * a][2 * bb] + bv, 0.f);
      float v01 = fmaxf(acc[2 * a][2 * bb + 1] + bv, 0.f);
      float v10 = fmaxf(acc[2 * a + 1][2 * bb] + bv, 0.f);
      float v11 = fmaxf(acc[2 * a + 1][2 * bb + 1] + bv, 0.f);
      float p = fmaxf(fmaxf(v00, v01), fmaxf(v10, v11));
      int gy = (tY >> 1) + (mrow0 >> 1) + a;
      int gx = (tX >> 1) + lhi * 2 + bb;
      if (gy < 18 && gx < 18)
        h2[(((size_t)b * 18 + gy) * 18 + gx) * 32 + co] = p;
    }
  }
}

// ---------------- K3a: dense partial GEMM (K-split, MFMA split-bf16) -------
__global__ __launch_bounds__(256) void k_dense_part(
    const float* __restrict__ h2, const float* __restrict__ w,
    float* __restrict__ part) {
  __shared__ __align__(16) unsigned short Ah[128 * 40];
  __shared__ __align__(16) unsigned short Al[128 * 40];
  __shared__ __align__(16) unsigned short Bh[64 * 40];
  __shared__ __align__(16) unsigned short Bl[64 * 40];
  int tid = threadIdx.x;
  int n0 = blockIdx.x * 64;   // 14 blocks (last ragged)
  int kc = blockIdx.y;        // 18 K-chunks of 576
  int wv = tid >> 6, lane = tid & 63;
  int lr = lane & 15, lhi = lane >> 4;
  f32x4 acc[8];
#pragma unroll
  for (int m = 0; m < 8; ++m) acc[m] = (f32x4){0.f, 0.f, 0.f, 0.f};
  for (int kt = 0; kt < 18; ++kt) {
    int kb = kc * 576 + kt * 32;
    if (kt) __syncthreads();
#pragma unroll
    for (int it = 0; it < 4; ++it) {
      int f = tid + it * 256;  // 0..1023 : 128 m rows x 8 float4
      int ml = f >> 3, kq = f & 7;
      float4 p = *(const float4*)(h2 + (size_t)ml * 10368 + kb + kq * 4);
      unsigned short h0, l0, h1, l1, h2_, l2_, h3, l3;
      split2t(p.x, h0, l0); split2t(p.y, h1, l1);
      split2t(p.z, h2_, l2_); split2t(p.w, h3, l3);
      s16x4 vh = {(short)h0, (short)h1, (short)h2_, (short)h3};
      s16x4 vl = {(short)l0, (short)l1, (short)l2_, (short)l3};
      *(s16x4*)(Ah + ml * 40 + kq * 4) = vh;
      *(s16x4*)(Al + ml * 40 + kq * 4) = vl;
    }
#pragma unroll
    for (int it = 0; it < 2; ++it) {
      int f = tid + it * 256;  // 0..511 : 32 k rows x 16 float4
      int kr = f >> 4, n4 = (f & 15) * 4;
      float4 p = {0.f, 0.f, 0.f, 0.f};
      if (n0 + n4 < 864)
        p = *(const float4*)(w + (size_t)(kb + kr) * 864 + n0 + n4);
      unsigned short hh, ll;
      split2t(p.x, hh, ll); Bh[(n4 + 0) * 40 + kr] = hh; Bl[(n4 + 0) * 40 + kr] = ll;
      split2t(p.y, hh, ll); Bh[(n4 + 1) * 40 + kr] = hh; Bl[(n4 + 1) * 40 + kr] = ll;
      split2t(p.z, hh, ll); Bh[(n4 + 2) * 40 + kr] = hh; Bl[(n4 + 2) * 40 + kr] = ll;
      split2t(p.w, hh, ll); Bh[(n4 + 3) * 40 + kr] = hh; Bl[(n4 + 3) * 40 + kr] = ll;
    }
    __syncthreads();
    bf16x8 bh_ = *(const bf16x8*)(Bh + (wv * 16 + lr) * 40 + lhi * 8);
    bf16x8 bl_ = *(const bf16x8*)(Bl + (wv * 16 + lr) * 40 + lhi * 8);
#pragma unroll
    for (int m = 0; m < 8; ++m) {
      bf16x8 ah = *(const bf16x8*)(Ah + (m * 16 + lr) * 40 + lhi * 8);
      bf16x8 al = *(const bf16x8*)(Al + (m * 16 + lr) * 40 + lhi * 8);
      acc[m] = __builtin_amdgcn_mfma_f32_16x16x32_bf16(ah, bh_, acc[m], 0, 0, 0);
      acc[m] = __builtin_amdgcn_mfma_f32_16x16x32_bf16(ah, bl_, acc[m], 0, 0, 0);
      acc[m] = __builtin_amdgcn_mfma_f32_16x16x32_bf16(al, bh_, acc[m], 0, 0, 0);
    }
  }
  int n = n0 + wv * 16 + lr;
  if (n < 864) {
#pragma unroll
    for (int m = 0; m < 8; ++m) {
#pragma unroll
      for (int r = 0; r < 4; ++r) {
        int mm = m * 16 + lhi * 4 + r;
        part[((size_t)kc * 128 + mm) * 864 + n] = acc[m][r];
      }
    }
  }
}

// ---------------- K_finprep: reduce partials -> filt (LDS) -> W1eff frags --
__global__ __launch_bounds__(256) void k_finprep(
    const float* __restrict__ part, const float* __restrict__ bias,
    const float* __restrict__ W1,
    unsigned short* __restrict__ Eh, unsigned short* __restrict__ El) {
  __shared__ float fl[864];
  int b = blockIdx.x;
  int tid = threadIdx.x;
  for (int e = tid; e < 864; e += 256) {
    float s = bias[e];
#pragma unroll
    for (int kc = 0; kc < 18; ++kc) s += part[(size_t)kc * 110592 + b * 864 + e];
    fl[e] = fmaxf(s, 0.f);
  }
  __syncthreads();
  int col = tid & 127;
  int k0 = tid >> 7;
  for (int k = k0; k < 64; k += 2) {
    float v;
    if (k < 12) {
      v = W1[k * 128 + col];
    } else if (k < 48) {
      int h = (k - 12) / 3, t = (k - 12) % 3;
      const float* wp = W1 + (12 + t) * 128 + col;  // + c*384 walks rows 12+3c+t
      const float* fp = fl + h * 72;
      float a0 = 0.f, a1 = 0.f, a2 = 0.f, a3 = 0.f;
      for (int c = 0; c < 72; c += 4) {
        a0 = fmaf(fp[c], wp[(size_t)c * 384], a0);
        a1 = fmaf(fp[c + 1], wp[(size_t)(c + 1) * 384], a1);
        a2 = fmaf(fp[c + 2], wp[(size_t)(c + 2) * 384], a2);
        a3 = fmaf(fp[c + 3], wp[(size_t)(c + 3) * 384], a3);
      }
      v = (a0 + a1) + (a2 + a3);
    } else {
      v = 0.f;
    }
    unsigned short hh, ll;
    split2(v, hh, ll);
    int ks = k >> 5, j = k & 7, a4 = (k >> 3) & 3;
    int l = a4 * 16 + (col & 15), nt = col >> 4;
    size_t o = (((size_t)b * 8 + nt) * 2 + ks) * 512 + l * 8 + j;
    Eh[o] = hh;
    El[o] = ll;
  }
}

// ---------------- K4: fused CA update (all-MFMA; packed-u32 u-exchange) ----
__global__ __launch_bounds__(256, 4) void k_ca(
    const float* __restrict__ x,
    const unsigned short* __restrict__ Eh, const unsigned short* __restrict__ El,
    const float* __restrict__ B1,
    const unsigned short* __restrict__ W2h, const unsigned short* __restrict__ W2l,
    const float* __restrict__ B2,
    float* __restrict__ xnew, float* __restrict__ aold,
    float* __restrict__ anew) {
  // staging: ia [16][120] f32 @0 (7680) | PAh @7680 (9216) | PAl @16896 (9216)
  // union after main GEMM: U32 @0 [64 px][132] u32 (33792) | mskL @33792 (256)
  __shared__ __align__(16) unsigned char S[34048];
  float* ia = (float*)S;
  unsigned short* PAh = (unsigned short*)(S + 7680);
  unsigned short* PAl = (unsigned short*)(S + 16896);
  unsigned* U32 = (unsigned*)S;
  float* mskL = (float*)(S + 33792);

  int tid = threadIdx.x;
  int b = blockIdx.y;
  int tx = (blockIdx.x & 7) * 8, ty = (blockIdx.x >> 3) * 8;
  int wv = tid >> 6, lane = tid & 63;
  int lr = lane & 15, lhi = lane >> 4;

  // prefetch W1eff B-frags (global, hides under phase A)
  bf16x8 bh[2][2], bl[2][2];
#pragma unroll
  for (int nt = 0; nt < 2; ++nt)
#pragma unroll
    for (int ks = 0; ks < 2; ++ks) {
      size_t base = (((size_t)b * 8 + (wv * 2 + nt)) * 2 + ks) * 512 + lane * 8;
      bh[nt][ks] = *(const bf16x8*)(Eh + base);
      bl[nt][ks] = *(const bf16x8*)(El + base);
    }
  // prefetch xo for phase D: px = wv*16 + lhi*4 + r, channel lr
  float xo[4];
#pragma unroll
  for (int r = 0; r < 4; ++r) {
    int px = wv * 16 + lhi * 4 + r;
    int gy = ty + (px >> 3), gx = tx + (px & 7);
    xo[r] = x[(((size_t)b * 64 + gy) * 64 + gx) * 16 + lr];
  }

  // ---- phase A: x halo -> ia; threefry -> mskL; zero PA k-pad 48..63
  if (tid < 200) {
    int px_ = tid >> 1, half = tid & 1;
    int hy = px_ / 10, hx = px_ - hy * 10;
    int pp = hy * 12 + hx;
    int gy = ty + hy - 1, gx = tx + hx - 1;
    float4 v0 = {0.f, 0.f, 0.f, 0.f}, v1 = {0.f, 0.f, 0.f, 0.f};
    if (gy >= 0 && gy < 64 && gx >= 0 && gx < 64) {
      const float* xp = x + (((size_t)b * 64 + gy) * 64 + gx) * 16 + half * 8;
      v0 = *(const float4*)xp;
      v1 = *(const float4*)(xp + 4);
    }
    int c0 = half * 8;
    ia[(c0 + 0) * 120 + pp] = v0.x; ia[(c0 + 1) * 120 + pp] = v0.y;
    ia[(c0 + 2) * 120 + pp] = v0.z; ia[(c0 + 3) * 120 + pp] = v0.w;
    ia[(c0 + 4) * 120 + pp] = v1.x; ia[(c0 + 5) * 120 + pp] = v1.y;
    ia[(c0 + 6) * 120 + pp] = v1.z; ia[(c0 + 7) * 120 + pp] = v1.w;
  }
  {
    if (tid >= 192) {
      int p = tid - 192;
      int gy = ty + (p >> 3), gx = tx + (p & 7);
      unsigned pix = (unsigned)(b * 4096 + gy * 64 + gx);
      mskL[p] = (tf42_uniform(pix) <= 0.5f) ? 1.f : 0.f;
    }
    const s16x4 z4 = {0, 0, 0, 0};
    if (wv == 2) {
#pragma unroll
      for (int g = 0; g < 4; ++g) *(s16x4*)(PAh + lane * 72 + 48 + 4 * g) = z4;
    }
    if (wv == 3) {
#pragma unroll
      for (int g = 0; g < 4; ++g) *(s16x4*)(PAl + lane * 72 + 48 + 4 * g) = z4;
    }
  }
  __syncthreads();

  // ---- phase P: perception of ch 4wv..4wv+3 -> PA cols 12wv..12wv+11
  {
    int py = lane >> 3, pxx = lane & 7;
    const float* pc0 = ia + (py + 1) * 12 + (pxx + 1);
    unsigned short oh[12], ol[12];
#pragma unroll
    for (int i = 0; i < 4; ++i) {
      const float* pc = pc0 + (wv * 4 + i) * 120;
      float n00 = pc[-13], n01 = pc[-12], n02 = pc[-11];
      float n10 = pc[-1],  n11 = pc[0],   n12 = pc[1];
      float n20 = pc[11],  n21 = pc[12],  n22 = pc[13];
      float pid = n11;
      float psx = ((n02 - n00) + 2.f * (n12 - n10) + (n22 - n20)) * 0.125f;
      float psy = ((n20 - n00) + 2.f * (n21 - n01) + (n22 - n02)) * 0.125f;
      split2t(pid, oh[3 * i + 0], ol[3 * i + 0]);
      split2t(psx, oh[3 * i + 1], ol[3 * i + 1]);
      split2t(psy, oh[3 * i + 2], ol[3 * i + 2]);
    }
    int off = lane * 72 + wv * 12;
#pragma unroll
    for (int g = 0; g < 3; ++g) {
      s16x4 vh = {(short)oh[4 * g], (short)oh[4 * g + 1],
                  (short)oh[4 * g + 2], (short)oh[4 * g + 3]};
      s16x4 vl = {(short)ol[4 * g], (short)ol[4 * g + 1],
                  (short)ol[4 * g + 2], (short)ol[4 * g + 3]};
      *(s16x4*)(PAh + off + 4 * g) = vh;
      *(s16x4*)(PAl + off + 4 * g) = vl;
    }
  }
  __syncthreads();

  // ---- phase M: main GEMM, 2 ks x 4 m x 2 nt x 3 passes
  f32x4 acc[4][2];
#pragma unroll
  for (int m = 0; m < 4; ++m)
#pragma unroll
    for (int nt = 0; nt < 2; ++nt)
      acc[m][nt] = (f32x4){0.f, 0.f, 0.f, 0.f};
#pragma unroll
  for (int ks = 0; ks < 2; ++ks) {
#pragma unroll
    for (int m = 0; m < 4; ++m) {
      int arow = m * 16 + lr;
      bf16x8 pah = *(const bf16x8*)(PAh + arow * 72 + ks * 32 + lhi * 8);
      bf16x8 pal = *(const bf16x8*)(PAl + arow * 72 + ks * 32 + lhi * 8);
#pragma unroll
      for (int nt = 0; nt < 2; ++nt) {
        acc[m][nt] = __builtin_amdgcn_mfma_f32_16x16x32_bf16(
            pah, bh[nt][ks], acc[m][nt], 0, 0, 0);
        acc[m][nt] = __builtin_amdgcn_mfma_f32_16x16x32_bf16(
            pah, bl[nt][ks], acc[m][nt], 0, 0, 0);
        acc[m][nt] = __builtin_amdgcn_mfma_f32_16x16x32_bf16(
            pal, bh[nt][ks], acc[m][nt], 0, 0, 0);
      }
    }
  }
  // prefetch W2 frags (consumed after next barrier)
  bf16x8 ch_[4], cl_[4];
#pragma unroll
  for (int ks = 0; ks < 4; ++ks) {
    ch_[ks] = *(const bf16x8*)(W2h + ks * 512 + lane * 8);
    cl_[ks] = *(const bf16x8*)(W2l + ks * 512 + lane * 8);
  }
  __syncthreads();  // PA dead -> U region may be written

  // ---- u-exchange: u = relu(acc + B1) packed (hi | lo<<16) into U32 [px][hid]
  int d0 = wv * 32;
  float b1v0 = B1[d0 + lr], b1v1 = B1[d0 + 16 + lr];
#pragma unroll
  for (int m = 0; m < 4; ++m)
#pragma unroll
    for (int nt = 0; nt < 2; ++nt) {
      float bv = nt ? b1v1 : b1v0;
      int hid = d0 + nt * 16 + lr;
#pragma unroll
      for (int r = 0; r < 4; ++r) {
        int px = m * 16 + lhi * 4 + r;
        U32[px * 132 + hid] = pack_bf2(fmaxf(acc[m][nt][r] + bv, 0.f));
      }
    }
  __syncthreads();

  // ---- dx MFMA: wave w computes px tile w (16 px x 16 e), K=128 hid
  union Cvt { unsigned d[4]; bf16x8 v8; };
  f32x4 acc2 = {0.f, 0.f, 0.f, 0.f};
  const unsigned* urow = U32 + (wv * 16 + lr) * 132;
#pragma unroll
  for (int ks = 0; ks < 4; ++ks) {
    u32x4 q0 = *(const u32x4*)(urow + ks * 32 + lhi * 8);
    u32x4 q1 = *(const u32x4*)(urow + ks * 32 + lhi * 8 + 4);
    Cvt ah, al;
#pragma unroll
    for (int i = 0; i < 2; ++i) {
      unsigned p0 = q0[2 * i], p1 = q0[2 * i + 1];
      ah.d[i] = (p0 & 0xffffu) | (p1 << 16);
      al.d[i] = (p0 >> 16) | (p1 & 0xffff0000u);
    }
#pragma unroll
    for (int i = 0; i < 2; ++i) {
      unsigned p0 = q1[2 * i], p1 = q1[2 * i + 1];
      ah.d[2 + i] = (p0 & 0xffffu) | (p1 << 16);
      al.d[2 + i] = (p0 >> 16) | (p1 & 0xffff0000u);
    }
    acc2 = __builtin_amdgcn_mfma_f32_16x16x32_bf16(ah.v8, ch_[ks], acc2, 0, 0, 0);
    acc2 = __builtin_amdgcn_mfma_f32_16x16x32_bf16(ah.v8, cl_[ks], acc2, 0, 0, 0);
    acc2 = __builtin_amdgcn_mfma_f32_16x16x32_bf16(al.v8, ch_[ks], acc2, 0, 0, 0);
  }

  // ---- phase D: dx + fire mask + write x_new + alphas (lane holds e=lr)
  float b2v = B2[lr];
#pragma unroll
  for (int r = 0; r < 4; ++r) {
    int px = wv * 16 + lhi * 4 + r;
    int gy = ty + (px >> 3), gx = tx + (px & 7);
    float m_ = mskL[px];
    float xn = xo[r] + (acc2[r] + b2v) * m_;
    size_t o = (((size_t)b * 64 + gy) * 64 + gx) * 16 + lr;
    xnew[o] = xn;
    if (lr == 3) {
      unsigned pix = (unsigned)(b * 4096 + gy * 64 + gx);
      aold[pix] = xo[r];
      anew[pix] = xn;
    }
  }
}

// ---------------- K5: living mask; ZERO only dead pixels (in place) --------
__global__ __launch_bounds__(256) void k_final(
    float* __restrict__ xnew, const float* __restrict__ aold,
    const float* __restrict__ anew) {
  int t = blockIdx.x * 256 + threadIdx.x;  // grid 2048*256 = 524288
  int gx = t & 63, gy = (t >> 6) & 63, b = t >> 12;
  float mo = -1e30f, mn = -1e30f;
  for (int dy = -1; dy <= 1; ++dy) {
    int yy = gy + dy; if (yy < 0 || yy >= 64) continue;
    for (int dx = -1; dx <= 1; ++dx) {
      int xx = gx + dx; if (xx < 0 || xx >= 64) continue;
      int p = b * 4096 + yy * 64 + xx;
      mo = fmaxf(mo, aold[p]);
      mn = fmaxf(mn, anew[p]);
    }
  }
  if (!(mo > 0.1f && mn > 0.1f)) {
    size_t base = (size_t)t * 16;
    const float4 z = {0.f, 0.f, 0.f, 0.f};
#pragma unroll
    for (int c4 = 0; c4 < 4; ++c4)
      *(float4*)(xnew + base + c4 * 4) = z;
  }
}

// ---------------- launch ----------------
extern "C" void kernel_launch(void* const* d_in, const int* in_sizes, int n_in,
                              void* d_out, int out_size, void* d_ws, size_t ws_size,
                              hipStream_t stream) {
  const float* x    = (const float*)d_in[0];
  const float* img  = (const float*)d_in[1];
  const float* g1   = (const float*)d_in[2];
  const float* be1  = (const float*)d_in[3];
  const float* m1   = (const float*)d_in[4];
  const float* v1   = (const float*)d_in[5];
  const float* w1c  = (const float*)d_in[6];
  const float* b1c  = (const float*)d_in[7];
  const float* g2   = (const float*)d_in[8];
  const float* be2  = (const float*)d_in[9];
  const float* m2   = (const float*)d_in[10];
  const float* v2   = (const float*)d_in[11];
  const float* w2c  = (const float*)d_in[12];
  const float* b2c  = (const float*)d_in[13];
  const float* dw   = (const float*)d_in[14];
  const float* db   = (const float*)d_in[15];
  const float* uw1  = (const float*)d_in[16];
  const float* ub1  = (const float*)d_in[17];
  const float* uw2  = (const float*)d_in[18];
  const float* ub2  = (const float*)d_in[19];

  char* ws = (char*)d_ws;
  float* h1   = (float*)(ws);                        // 21,233,664 B (dead after conv2)
  float* part = h1;                                  // aliased (written by dense)
  float* h2   = (float*)(ws + 21233664);             // 5,308,416 B
  float* aold = (float*)(ws + 26542080);             // 2,097,152 B
  float* anew = (float*)(ws + 28639232);             // 2,097,152 B
  unsigned short* W2Bh = (unsigned short*)(ws + 30736384);  // 4,096 B
  unsigned short* W2Bl = (unsigned short*)(ws + 30740480);  // 4,096 B
  unsigned short* Wc2h = (unsigned short*)(ws + 30744576);  // 18,432 B
  unsigned short* Wc2l = (unsigned short*)(ws + 30763008);  // 18,432 B
  unsigned short* Wc1h = (unsigned short*)(ws + 30781440);  // 6,144 B
  unsigned short* Wc1l = (unsigned short*)(ws + 30787584);  // 6,144 B
  unsigned short* W1Eh = (unsigned short*)(ws + 30793728);  // 2,097,152 B
  unsigned short* W1El = (unsigned short*)(ws + 32890880);  // 2,097,152 B
  // total 34,988,032 B
  float* xnew = (float*)d_out;                       // (128,64,64,16) f32

  k_prep_w<<<49, 256, 0, stream>>>(w1c, w2c, uw2, Wc1h, Wc1l, Wc2h, Wc2l,
                                   W2Bh, W2Bl);
  k_conv1<<<dim3(25, 128), 256, 0, stream>>>(img, g1, be1, m1, v1, Wc1h, Wc1l,
                                             b1c, g2, be2, m2, v2, h1);
  k_conv2<<<dim3(9, 128), 256, 0, stream>>>(h1, Wc2h, Wc2l, b2c, h2);
  k_dense_part<<<dim3(14, 18), 256, 0, stream>>>(h2, dw, part);
  k_finprep<<<128, 256, 0, stream>>>(part, db, uw1, W1Eh, W1El);
  k_ca<<<dim3(64, 128), 256, 0, stream>>>(x, W1Eh, W1El, ub1, W2Bh, W2Bl, ub2,
                                          xnew, aold, anew);
  k_final<<<2048, 256, 0, stream>>>(xnew, aold, anew);
}